// Round 1
// baseline (30034.937 us; speedup 1.0000x reference)
//
#include <hip/hip_runtime.h>
#include <math.h>

#define B_ 16
#define T_ 512
#define D_ 1024
#define H_ 4
#define DH_ 256
#define FF_ 4096
#define M_ (B_*T_)
#define THRESH_ 0.3f
#define EPS_ 1e-5f

#define GF_RELU 1
#define GF_RES  2

// ---------------------------------------------------------------------------
// Generic tiled fp32 GEMM: out[M,N] = A[M,K] * Bt[N,K]^T + bias (+res)(relu)
// block (16,16), tile 64x64, K-step 16, 4x4 micro-tile per thread.
// Only M needs bounds-guarding (N multiple of 64, K multiple of 16 in all uses).
// ---------------------------------------------------------------------------
__global__ __launch_bounds__(256)
void gemm_bt(const float* __restrict__ A, const float* __restrict__ Bt,
             const float* __restrict__ bias, const float* __restrict__ res,
             float* __restrict__ out, int M, int N, int K, int flags)
{
  __shared__ float As[16][68];
  __shared__ float Bs[16][68];
  const int n0 = blockIdx.x << 6;
  const int m0 = blockIdx.y << 6;
  const int tx = threadIdx.x, ty = threadIdx.y;
  const int tid = (ty << 4) + tx;
  const int lr = tid >> 2;
  const int lc = (tid & 3) << 2;
  float c[4][4] = {};
  for (int k0 = 0; k0 < K; k0 += 16) {
    float4 av = make_float4(0.f, 0.f, 0.f, 0.f);
    if (m0 + lr < M)
      av = *(const float4*)(A + (size_t)(m0 + lr) * K + k0 + lc);
    const float4 bv = *(const float4*)(Bt + (size_t)(n0 + lr) * K + k0 + lc);
    As[lc + 0][lr] = av.x; As[lc + 1][lr] = av.y;
    As[lc + 2][lr] = av.z; As[lc + 3][lr] = av.w;
    Bs[lc + 0][lr] = bv.x; Bs[lc + 1][lr] = bv.y;
    Bs[lc + 2][lr] = bv.z; Bs[lc + 3][lr] = bv.w;
    __syncthreads();
#pragma unroll
    for (int k = 0; k < 16; ++k) {
      const float4 a = *(const float4*)(&As[k][ty << 2]);
      const float4 b = *(const float4*)(&Bs[k][tx << 2]);
      c[0][0] += a.x*b.x; c[0][1] += a.x*b.y; c[0][2] += a.x*b.z; c[0][3] += a.x*b.w;
      c[1][0] += a.y*b.x; c[1][1] += a.y*b.y; c[1][2] += a.y*b.z; c[1][3] += a.y*b.w;
      c[2][0] += a.z*b.x; c[2][1] += a.z*b.y; c[2][2] += a.z*b.z; c[2][3] += a.z*b.w;
      c[3][0] += a.w*b.x; c[3][1] += a.w*b.y; c[3][2] += a.w*b.z; c[3][3] += a.w*b.w;
    }
    __syncthreads();
  }
  const int n = n0 + (tx << 2);
  const float4 bb = *(const float4*)(bias + n);
#pragma unroll
  for (int i = 0; i < 4; ++i) {
    const int m = m0 + (ty << 2) + i;
    if (m >= M) break;
    float4 v = make_float4(c[i][0] + bb.x, c[i][1] + bb.y,
                           c[i][2] + bb.z, c[i][3] + bb.w);
    if (flags & GF_RES) {
      const float4 r = *(const float4*)(res + (size_t)m * N + n);
      v.x += r.x; v.y += r.y; v.z += r.z; v.w += r.w;
    }
    if (flags & GF_RELU) {
      v.x = fmaxf(v.x, 0.f); v.y = fmaxf(v.y, 0.f);
      v.z = fmaxf(v.z, 0.f); v.w = fmaxf(v.w, 0.f);
    }
    *(float4*)(out + (size_t)m * N + n) = v;
  }
}

// ---------------------------------------------------------------------------
// Attention scores: sc[bh][t][s] = q[t].k[s]/16, -inf where s>t.
// grid (T/64 s-tiles, T/32 t-tiles, B*H). Blocks fully above diagonal skipped,
// and are never read downstream (softmax/PV bound = 64-aligned).
// ---------------------------------------------------------------------------
__global__ __launch_bounds__(256)
void attn_scores(const float* __restrict__ qkv, float* __restrict__ sc)
{
  const int bh = blockIdx.z;
  const int b = bh >> 2, h = bh & 3;
  const int t0 = blockIdx.y << 5;
  const int s0 = blockIdx.x << 6;
  if (s0 > t0 + 31) return;
  __shared__ float Qs[16][36];
  __shared__ float Ks[16][68];
  const int tx = threadIdx.x, ty = threadIdx.y;
  const int tid = (ty << 4) + tx;
  const int qr = tid >> 3;
  const int qc = (tid & 7) << 1;
  const int kr = tid >> 2;
  const int kc = (tid & 3) << 2;
  float c[2][4] = {};
  const float* qbase = qkv + (size_t)(b * T_) * (3 * D_) + h * DH_;
  const float* kbase = qbase + D_;
  for (int k0 = 0; k0 < DH_; k0 += 16) {
    const float2 qv = *(const float2*)(qbase + (size_t)(t0 + qr) * (3 * D_) + k0 + qc);
    const float4 kv = *(const float4*)(kbase + (size_t)(s0 + kr) * (3 * D_) + k0 + kc);
    Qs[qc + 0][qr] = qv.x; Qs[qc + 1][qr] = qv.y;
    Ks[kc + 0][kr] = kv.x; Ks[kc + 1][kr] = kv.y;
    Ks[kc + 2][kr] = kv.z; Ks[kc + 3][kr] = kv.w;
    __syncthreads();
#pragma unroll
    for (int k = 0; k < 16; ++k) {
      const float a0 = Qs[k][(ty << 1) + 0];
      const float a1 = Qs[k][(ty << 1) + 1];
      const float4 bv = *(const float4*)(&Ks[k][tx << 2]);
      c[0][0] += a0*bv.x; c[0][1] += a0*bv.y; c[0][2] += a0*bv.z; c[0][3] += a0*bv.w;
      c[1][0] += a1*bv.x; c[1][1] += a1*bv.y; c[1][2] += a1*bv.z; c[1][3] += a1*bv.w;
    }
    __syncthreads();
  }
  float* scb = sc + (size_t)bh * T_ * T_;
#pragma unroll
  for (int i = 0; i < 2; ++i) {
    const int t = t0 + (ty << 1) + i;
#pragma unroll
    for (int j = 0; j < 4; ++j) {
      const int s = s0 + (tx << 2) + j;
      float v = c[i][j] * 0.0625f;
      if (s > t) v = -INFINITY;
      scb[(size_t)t * T_ + s] = v;
    }
  }
}

// ---------------------------------------------------------------------------
// Row softmax over cols [0, bound) where bound = 64*(t/64+1).
// ---------------------------------------------------------------------------
__global__ __launch_bounds__(256)
void softmax_rows(float* __restrict__ sc)
{
  const int row = blockIdx.x;
  const int t = row & (T_ - 1);
  const int bound = ((t >> 6) + 1) << 6;
  float* p = sc + (size_t)row * T_;
  const int tid = threadIdx.x;
  const int wave = tid >> 6, lane = tid & 63;
  float v0 = (tid < bound) ? p[tid] : -INFINITY;
  float v1 = (tid + 256 < bound) ? p[tid + 256] : -INFINITY;
  float m = fmaxf(v0, v1);
  for (int off = 32; off; off >>= 1) m = fmaxf(m, __shfl_down(m, off, 64));
  __shared__ float wm[4];
  __shared__ float wsum[4];
  if (!lane) wm[wave] = m;
  __syncthreads();
  m = fmaxf(fmaxf(wm[0], wm[1]), fmaxf(wm[2], wm[3]));
  float e0 = (tid < bound) ? __expf(v0 - m) : 0.f;
  float e1 = (tid + 256 < bound) ? __expf(v1 - m) : 0.f;
  float s = e0 + e1;
  for (int off = 32; off; off >>= 1) s += __shfl_down(s, off, 64);
  if (!lane) wsum[wave] = s;
  __syncthreads();
  s = wsum[0] + wsum[1] + wsum[2] + wsum[3];
  const float inv = 1.f / s;
  if (tid < bound) p[tid] = e0 * inv;
  if (tid + 256 < bound) p[tid + 256] = e1 * inv;
}

// ---------------------------------------------------------------------------
// P·V: ao[b, t, h*DH+d] = sum_s P[t][s] * V[s][d].  grid (DH/64, T/32, B*H).
// ---------------------------------------------------------------------------
__global__ __launch_bounds__(256)
void attn_pv(const float* __restrict__ sc, const float* __restrict__ qkv,
             float* __restrict__ ao)
{
  const int bh = blockIdx.z, b = bh >> 2, h = bh & 3;
  const int t0 = blockIdx.y << 5;
  const int d0 = blockIdx.x << 6;
  const int kmax = ((t0 >> 6) + 1) << 6;
  __shared__ float Ps[16][36];
  __shared__ float Vs[16][68];
  const int tx = threadIdx.x, ty = threadIdx.y;
  const int tid = (ty << 4) + tx;
  const int pr = tid >> 3;
  const int pc = (tid & 7) << 1;
  const int vr = tid >> 4;
  const int vc = (tid & 15) << 2;
  float c[2][4] = {};
  const float* scb = sc + (size_t)bh * T_ * T_;
  const float* vbase = qkv + (size_t)(b * T_) * (3 * D_) + 2 * D_ + h * DH_;
  for (int k0 = 0; k0 < kmax; k0 += 16) {
    const float2 pv = *(const float2*)(scb + (size_t)(t0 + pr) * T_ + k0 + pc);
    const float4 vv = *(const float4*)(vbase + (size_t)(k0 + vr) * (3 * D_) + d0 + vc);
    Ps[pc + 0][pr] = pv.x; Ps[pc + 1][pr] = pv.y;
    *(float4*)(&Vs[vr][vc]) = vv;
    __syncthreads();
#pragma unroll
    for (int k = 0; k < 16; ++k) {
      const float a0 = Ps[k][(ty << 1) + 0];
      const float a1 = Ps[k][(ty << 1) + 1];
      const float4 bv = *(const float4*)(&Vs[k][tx << 2]);
      c[0][0] += a0*bv.x; c[0][1] += a0*bv.y; c[0][2] += a0*bv.z; c[0][3] += a0*bv.w;
      c[1][0] += a1*bv.x; c[1][1] += a1*bv.y; c[1][2] += a1*bv.z; c[1][3] += a1*bv.w;
    }
    __syncthreads();
  }
  float* aob = ao + (size_t)(b * T_ + t0) * D_ + h * DH_ + d0;
#pragma unroll
  for (int i = 0; i < 2; ++i) {
    float4 v = make_float4(c[i][0], c[i][1], c[i][2], c[i][3]);
    *(float4*)(aob + (size_t)((ty << 1) + i) * D_ + (tx << 2)) = v;
  }
}

// ---------------------------------------------------------------------------
// LayerNorm over D=1024. grid M_, block 256 (4 elems/thread).
// ---------------------------------------------------------------------------
__global__ __launch_bounds__(256)
void layernorm_k(const float* __restrict__ in, const float* __restrict__ g,
                 const float* __restrict__ bta, float* __restrict__ out)
{
  const int row = blockIdx.x;
  const int tid = threadIdx.x;
  const int wave = tid >> 6, lane = tid & 63;
  const float4 v = *(const float4*)(in + (size_t)row * D_ + (tid << 2));
  float s = v.x + v.y + v.z + v.w;
  float ss = v.x*v.x + v.y*v.y + v.z*v.z + v.w*v.w;
  for (int off = 32; off; off >>= 1) {
    s  += __shfl_down(s, off, 64);
    ss += __shfl_down(ss, off, 64);
  }
  __shared__ float ra[4], rb[4];
  if (!lane) { ra[wave] = s; rb[wave] = ss; }
  __syncthreads();
  s  = ra[0] + ra[1] + ra[2] + ra[3];
  ss = rb[0] + rb[1] + rb[2] + rb[3];
  const float mu = s * (1.f / (float)D_);
  const float var = ss * (1.f / (float)D_) - mu * mu;
  const float rstd = rsqrtf(var + EPS_);
  const float4 gv = *(const float4*)(g + (tid << 2));
  const float4 bv = *(const float4*)(bta + (tid << 2));
  float4 o;
  o.x = (v.x - mu) * rstd * gv.x + bv.x;
  o.y = (v.y - mu) * rstd * gv.y + bv.y;
  o.z = (v.z - mu) * rstd * gv.z + bv.z;
  o.w = (v.w - mu) * rstd * gv.w + bv.w;
  *(float4*)(out + (size_t)row * D_ + (tid << 2)) = o;
}

// ---------------------------------------------------------------------------
// Head layer 2 + sigmoid: s[m] = sigmoid(h1[m,:512].w2 + b). One wave per row.
// ---------------------------------------------------------------------------
__global__ __launch_bounds__(256)
void head2_sigmoid(const float* __restrict__ h1, const float* __restrict__ w2,
                   const float* __restrict__ b2, float* __restrict__ sout)
{
  const int tid = threadIdx.x;
  const int wave = tid >> 6, lane = tid & 63;
  const int m = (blockIdx.x << 2) + wave;
  const float* hr = h1 + (size_t)m * 512;
  float s = 0.f;
#pragma unroll
  for (int i = 0; i < 8; ++i) s += hr[i * 64 + lane] * w2[i * 64 + lane];
  for (int off = 32; off; off >>= 1) s += __shfl_down(s, off, 64);
  if (!lane) sout[m] = 1.f / (1.f + expf(-(s + b2[0])));
}

// ---------------------------------------------------------------------------
// Per-batch selection: w = first argmin of (s<0.3 ? s : inf); has_bad; counts.
// ---------------------------------------------------------------------------
__global__ __launch_bounds__(256)
void select_worst(const float* __restrict__ s, int* __restrict__ w,
                  int* __restrict__ hasbad, int* __restrict__ counts)
{
  const int b = blockIdx.x, tid = threadIdx.x;
  const float* sr = s + b * T_;
  float bv = INFINITY; int bi = 0;
  for (int i = tid; i < T_; i += 256) {
    const float v = sr[i];
    const float cand = (v < THRESH_) ? v : INFINITY;
    if (cand < bv || (cand == bv && i < bi)) { bv = cand; bi = i; }
  }
  __shared__ float rv[256];
  __shared__ int ri[256];
  rv[tid] = bv; ri[tid] = bi;
  __syncthreads();
  for (int str = 128; str; str >>= 1) {
    if (tid < str) {
      const float v2 = rv[tid + str]; const int i2 = ri[tid + str];
      if (v2 < rv[tid] || (v2 == rv[tid] && i2 < ri[tid])) { rv[tid] = v2; ri[tid] = i2; }
    }
    __syncthreads();
  }
  if (!tid) {
    const int bad = (rv[0] < INFINITY) ? 1 : 0;
    w[b] = ri[0];
    hasbad[b] = bad;
    counts[b] += bad;
  }
}

// ---------------------------------------------------------------------------
// Build correction-MLP input: [cur, mean(valid window)] per batch.
// ---------------------------------------------------------------------------
__global__ __launch_bounds__(256)
void gather_cinp(const float* __restrict__ corr, const int* __restrict__ w,
                 float* __restrict__ cinp)
{
  const int b = blockIdx.x, tid = threadIdx.x;
  const int wi = w[b];
  const float* base = corr + (size_t)b * T_ * D_;
  const int nv = 3 - (wi == 0 ? 1 : 0) - (wi == T_ - 1 ? 1 : 0);
  const float inv = 1.f / (float)nv;
  const int d = tid << 2;
  const float4 cur = *(const float4*)(base + (size_t)wi * D_ + d);
  float4 acc = cur;
  if (wi > 0) {
    const float4 p = *(const float4*)(base + (size_t)(wi - 1) * D_ + d);
    acc.x += p.x; acc.y += p.y; acc.z += p.z; acc.w += p.w;
  }
  if (wi < T_ - 1) {
    const float4 p = *(const float4*)(base + (size_t)(wi + 1) * D_ + d);
    acc.x += p.x; acc.y += p.y; acc.z += p.z; acc.w += p.w;
  }
  acc.x *= inv; acc.y *= inv; acc.z *= inv; acc.w *= inv;
  *(float4*)(cinp + (size_t)b * (2 * D_) + d) = cur;
  *(float4*)(cinp + (size_t)b * (2 * D_) + D_ + d) = acc;
}

__global__ __launch_bounds__(256)
void apply_corr(float* __restrict__ corr, const int* __restrict__ w,
                const int* __restrict__ hasbad, const float* __restrict__ ns)
{
  const int b = blockIdx.x;
  if (!hasbad[b]) return;
  const int wi = w[b], tid = threadIdx.x;
  *(float4*)(corr + (size_t)(b * T_ + wi) * D_ + (tid << 2)) =
      *(const float4*)(ns + (size_t)b * D_ + (tid << 2));
}

__global__ __launch_bounds__(256)
void init_copy(const float* __restrict__ chain, float* __restrict__ corr,
               int* __restrict__ counts)
{
  const size_t i = ((size_t)blockIdx.x * 256 + threadIdx.x) << 2;
  *(float4*)(corr + i) = *(const float4*)(chain + i);
  if (blockIdx.x == 0 && threadIdx.x < B_) counts[threadIdx.x] = 0;
}

__global__ __launch_bounds__(256)
void finalize_k(const float* __restrict__ s0, const float* __restrict__ fs,
                const int* __restrict__ cnt, float* __restrict__ oc,
                float* __restrict__ oi)
{
  const int b = blockIdx.x, tid = threadIdx.x;
  const int wave = tid >> 6, lane = tid & 63;
  float a = s0[b * T_ + tid] + s0[b * T_ + tid + 256];
  float c = fs[b * T_ + tid] + fs[b * T_ + tid + 256];
  for (int off = 32; off; off >>= 1) {
    a += __shfl_down(a, off, 64);
    c += __shfl_down(c, off, 64);
  }
  __shared__ float ra[4], rc[4];
  if (!lane) { ra[wave] = a; rc[wave] = c; }
  __syncthreads();
  if (!tid) {
    const float as = ra[0] + ra[1] + ra[2] + ra[3];
    const float cs = rc[0] + rc[1] + rc[2] + rc[3];
    oc[b] = (float)cnt[b];
    oi[b] = (cs > as) ? 1.f : 0.f;
  }
}

// ---------------------------------------------------------------------------
extern "C" void kernel_launch(void* const* d_in, const int* in_sizes, int n_in,
                              void* d_out, int out_size, void* d_ws, size_t ws_size,
                              hipStream_t stream)
{
  const float* chain  = (const float*)d_in[0];
  const float* Wqkv   = (const float*)d_in[1];
  const float* bqkv   = (const float*)d_in[2];
  const float* Wo     = (const float*)d_in[3];
  const float* bo     = (const float*)d_in[4];
  const float* ln1g   = (const float*)d_in[5];
  const float* ln1b   = (const float*)d_in[6];
  const float* W1     = (const float*)d_in[7];
  const float* b1     = (const float*)d_in[8];
  const float* W2     = (const float*)d_in[9];
  const float* b2     = (const float*)d_in[10];
  const float* ln2g   = (const float*)d_in[11];
  const float* ln2b   = (const float*)d_in[12];
  const float* rhW1   = (const float*)d_in[13];
  const float* rhb1   = (const float*)d_in[14];
  const float* rhW2   = (const float*)d_in[15];
  const float* rhb2   = (const float*)d_in[16];
  const float* corW1  = (const float*)d_in[17];
  const float* corb1  = (const float*)d_in[18];
  const float* corW2  = (const float*)d_in[19];
  const float* corb2  = (const float*)d_in[20];

  float* ws = (float*)d_ws;
  // region layout (floats); aliases chosen so live ranges never overlap
  float* X    = ws;                 // 8388608  (x activations)
  float* QKV  = ws + 8388608;       // 25165824 (qkv)
  float* SC   = ws + 33554432;      // 16777216 (attn scores)
  float* AO   = ws + 50331648;      // 8388608  (attn output concat)
  float* PRE  = SC;                 // o-proj out (pre-LN1) — SC dead by then
  float* Hb   = QKV;                // ff hidden (33554432 fl, spans QKV+part SC)
  float* E    = AO;                 // ff2 out (pre-LN2) — AO dead by then
  float* HH   = AO;                 // head hidden (8192x512) — AO dead by then
  float* s0buf = ws + 58720256;     // 8192
  float* sbuf  = s0buf + 8192;      // 8192
  float* cinp  = sbuf + 8192;       // 32768
  float* corrH = cinp + 32768;      // 32768
  float* nstep = corrH + 32768;     // 16384
  int* wbuf   = (int*)(nstep + 16384);
  int* badbuf = wbuf + 16;
  int* cntbuf = badbuf + 16;

  float* outCorr   = (float*)d_out;          // 8388608
  float* outCounts = outCorr + 8388608;      // 16
  float* outFS     = outCounts + 16;         // 8192
  float* outImpr   = outFS + 8192;           // 16

  const dim3 blk2(16, 16);

  auto run_prm = [&](const float* xin, float* scoresOut) {
    const float* x = xin;
    for (int l = 0; l < 2; ++l) {
      const float* Wqkv_l = Wqkv + (size_t)l * 3 * D_ * D_;
      const float* bqkv_l = bqkv + (size_t)l * 3 * D_;
      const float* Wo_l   = Wo + (size_t)l * D_ * D_;
      const float* bo_l   = bo + (size_t)l * D_;
      const float* W1_l   = W1 + (size_t)l * FF_ * D_;
      const float* b1_l   = b1 + (size_t)l * FF_;
      const float* W2_l   = W2 + (size_t)l * D_ * FF_;
      const float* b2_l   = b2 + (size_t)l * D_;

      gemm_bt<<<dim3(48, 128), blk2, 0, stream>>>(x, Wqkv_l, bqkv_l, nullptr,
                                                  QKV, M_, 3 * D_, D_, 0);
      attn_scores<<<dim3(8, 16, 64), blk2, 0, stream>>>(QKV, SC);
      softmax_rows<<<dim3(64 * T_), dim3(256), 0, stream>>>(SC);
      attn_pv<<<dim3(4, 16, 64), blk2, 0, stream>>>(SC, QKV, AO);
      gemm_bt<<<dim3(16, 128), blk2, 0, stream>>>(AO, Wo_l, bo_l, x,
                                                  PRE, M_, D_, D_, GF_RES);
      layernorm_k<<<dim3(M_), dim3(256), 0, stream>>>(PRE, ln1g + l * D_,
                                                      ln1b + l * D_, X);
      gemm_bt<<<dim3(64, 128), blk2, 0, stream>>>(X, W1_l, b1_l, nullptr,
                                                  Hb, M_, FF_, D_, GF_RELU);
      gemm_bt<<<dim3(16, 128), blk2, 0, stream>>>(Hb, W2_l, b2_l, X,
                                                  E, M_, D_, FF_, GF_RES);
      layernorm_k<<<dim3(M_), dim3(256), 0, stream>>>(E, ln2g + l * D_,
                                                      ln2b + l * D_, X);
      x = X;
    }
    gemm_bt<<<dim3(8, 128), blk2, 0, stream>>>(X, rhW1, rhb1, nullptr,
                                               HH, M_, 512, D_, GF_RELU);
    head2_sigmoid<<<dim3(M_ / 4), dim3(256), 0, stream>>>(HH, rhW2, rhb2, scoresOut);
  };

  auto run_iter = [&](const float* sPtr) {
    select_worst<<<dim3(B_), dim3(256), 0, stream>>>(sPtr, wbuf, badbuf, cntbuf);
    gather_cinp<<<dim3(B_), dim3(256), 0, stream>>>(outCorr, wbuf, cinp);
    gemm_bt<<<dim3(32, 1), blk2, 0, stream>>>(cinp, corW1, corb1, nullptr,
                                              corrH, B_, 2 * D_, 2 * D_, GF_RELU);
    gemm_bt<<<dim3(16, 1), blk2, 0, stream>>>(corrH, corW2, corb2, nullptr,
                                              nstep, B_, D_, 2 * D_, 0);
    apply_corr<<<dim3(B_), dim3(256), 0, stream>>>(outCorr, wbuf, badbuf, nstep);
  };

  init_copy<<<dim3(8192), dim3(256), 0, stream>>>(chain, outCorr, cntbuf);

  // prm #1: scores0 = prm(chain). Iteration 1 reuses it (corrected == chain).
  run_prm(chain, s0buf);
  run_iter(s0buf);
  // iterations 2 and 3
  run_prm(outCorr, sbuf);
  run_iter(sbuf);
  run_prm(outCorr, sbuf);
  run_iter(sbuf);
  // final scores -> d_out directly
  run_prm(outCorr, outFS);
  finalize_k<<<dim3(B_), dim3(256), 0, stream>>>(s0buf, outFS, cntbuf,
                                                 outCounts, outImpr);
  (void)in_sizes; (void)n_in; (void)out_size; (void)ws_size;
}

// Round 2
// 6514.227 us; speedup vs baseline: 4.6107x; 4.6107x over previous
//
#include <hip/hip_runtime.h>
#include <math.h>

#define B_ 16
#define T_ 512
#define D_ 1024
#define H_ 4
#define DH_ 256
#define FF_ 4096
#define M_ (B_*T_)
#define THRESH_ 0.3f
#define EPS_ 1e-5f

#define GF_RELU 1
#define GF_RES  2
#define GF_OUTBF16 4

typedef unsigned short ushort_t;
typedef unsigned int uint_t;

using s16x8 = __attribute__((ext_vector_type(8))) short;
using f32x4 = __attribute__((ext_vector_type(4))) float;

typedef const __attribute__((address_space(1))) void* gas_ptr;
typedef __attribute__((address_space(3))) void* lds_ptr;

static __device__ __forceinline__ ushort_t f2bf(float f) {
  uint_t x = __float_as_uint(f);
  return (ushort_t)((x + 0x7FFFu + ((x >> 16) & 1u)) >> 16);  // RNE
}
static __device__ __forceinline__ float bf2f(ushort_t u) {
  return __uint_as_float(((uint_t)u) << 16);
}

// ---------------------------------------------------------------------------
// fp32 -> bf16 conversion (4 elems/thread)
// ---------------------------------------------------------------------------
__global__ __launch_bounds__(256)
void cvt_f32_bf16(const float* __restrict__ in, ushort_t* __restrict__ out, int n)
{
  const int i = (blockIdx.x * 256 + threadIdx.x) << 2;
  if (i >= n) return;
  const float4 v = *(const float4*)(in + i);
  ushort4 o;
  o.x = f2bf(v.x); o.y = f2bf(v.y); o.z = f2bf(v.z); o.w = f2bf(v.w);
  *(ushort4*)(out + i) = o;
}

// ---------------------------------------------------------------------------
// bf16 MFMA GEMM (m97 structure): out[M,N] = A[M,K] * Bt[N,K]^T + bias
// (+ bf16 residual)(relu). Tile 128x128, BK=32, 4 waves of 4x4 16x16x32 MFMAs.
// M %128==0, N%128==0, K%32==0 in all uses -> no bounds checks.
// A, Bt bf16; out fp32 or bf16 per flags.
// ---------------------------------------------------------------------------
__global__ __launch_bounds__(256)
void gemm_bf16(const ushort_t* __restrict__ A, const ushort_t* __restrict__ Bt,
               const float* __restrict__ bias, const ushort_t* __restrict__ res,
               float* __restrict__ outF, ushort_t* __restrict__ outB,
               int M, int N, int K, int flags)
{
  __shared__ ushort_t As[128 * 32];
  __shared__ ushort_t Bs[128 * 32];
  const int n0 = blockIdx.x << 7;
  const int m0 = blockIdx.y << 7;
  const int tid = threadIdx.x;
  const int wv = tid >> 6, ln = tid & 63;
  const int wm = (wv >> 1) << 6;     // wave m-offset in tile: 0 / 64
  const int wn = (wv & 1) << 6;      // wave n-offset in tile: 0 / 64
  const int lrow = ln & 15, quad = ln >> 4;

  f32x4 acc[4][4] = {};

  const ushort_t* ga = A + (size_t)(m0 + wv * 16 + (ln >> 2)) * K + ((ln & 3) << 3);
  const ushort_t* gb = Bt + (size_t)(n0 + wv * 16 + (ln >> 2)) * K + ((ln & 3) << 3);
  ushort_t* lA = &As[wv * 512];
  ushort_t* lB = &Bs[wv * 512];

  for (int k0 = 0; k0 < K; k0 += 32) {
    __builtin_amdgcn_global_load_lds((gas_ptr)(const void*)ga,
                                     (lds_ptr)(void*)lA, 16, 0, 0);
    __builtin_amdgcn_global_load_lds((gas_ptr)(const void*)(ga + (size_t)64 * K),
                                     (lds_ptr)(void*)(lA + 2048), 16, 0, 0);
    __builtin_amdgcn_global_load_lds((gas_ptr)(const void*)gb,
                                     (lds_ptr)(void*)lB, 16, 0, 0);
    __builtin_amdgcn_global_load_lds((gas_ptr)(const void*)(gb + (size_t)64 * K),
                                     (lds_ptr)(void*)(lB + 2048), 16, 0, 0);
    ga += 32; gb += 32;
    __syncthreads();
    s16x8 af[4], bfr[4];
#pragma unroll
    for (int i = 0; i < 4; ++i)
      af[i] = *(const s16x8*)(&As[(wm + i * 16 + lrow) * 32 + quad * 8]);
#pragma unroll
    for (int j = 0; j < 4; ++j)
      bfr[j] = *(const s16x8*)(&Bs[(wn + j * 16 + lrow) * 32 + quad * 8]);
#pragma unroll
    for (int i = 0; i < 4; ++i)
#pragma unroll
      for (int j = 0; j < 4; ++j)
        acc[i][j] = __builtin_amdgcn_mfma_f32_16x16x32_bf16(af[i], bfr[j],
                                                            acc[i][j], 0, 0, 0);
    __syncthreads();
  }

#pragma unroll
  for (int i = 0; i < 4; ++i) {
    const int row0 = m0 + wm + i * 16 + quad * 4;
#pragma unroll
    for (int j = 0; j < 4; ++j) {
      const int c = n0 + wn + j * 16 + lrow;
      const float bb = bias[c];
#pragma unroll
      for (int r = 0; r < 4; ++r) {
        float v = acc[i][j][r] + bb;
        const size_t idx = (size_t)(row0 + r) * N + c;
        if (flags & GF_RES) v += bf2f(res[idx]);
        if (flags & GF_RELU) v = fmaxf(v, 0.f);
        if (flags & GF_OUTBF16) outB[idx] = f2bf(v);
        else outF[idx] = v;
      }
    }
  }
}

// ---------------------------------------------------------------------------
// fp32 tiled GEMM (kept for the tiny correction MLP, M=16).
// ---------------------------------------------------------------------------
__global__ __launch_bounds__(256)
void gemm_bt(const float* __restrict__ A, const float* __restrict__ Bt,
             const float* __restrict__ bias, float* __restrict__ out,
             int M, int N, int K, int flags)
{
  __shared__ float As[16][68];
  __shared__ float Bs[16][68];
  const int n0 = blockIdx.x << 6;
  const int m0 = blockIdx.y << 6;
  const int tx = threadIdx.x, ty = threadIdx.y;
  const int tid = (ty << 4) + tx;
  const int lr = tid >> 2;
  const int lc = (tid & 3) << 2;
  float c[4][4] = {};
  for (int k0 = 0; k0 < K; k0 += 16) {
    float4 av = make_float4(0.f, 0.f, 0.f, 0.f);
    if (m0 + lr < M)
      av = *(const float4*)(A + (size_t)(m0 + lr) * K + k0 + lc);
    const float4 bv = *(const float4*)(Bt + (size_t)(n0 + lr) * K + k0 + lc);
    As[lc + 0][lr] = av.x; As[lc + 1][lr] = av.y;
    As[lc + 2][lr] = av.z; As[lc + 3][lr] = av.w;
    Bs[lc + 0][lr] = bv.x; Bs[lc + 1][lr] = bv.y;
    Bs[lc + 2][lr] = bv.z; Bs[lc + 3][lr] = bv.w;
    __syncthreads();
#pragma unroll
    for (int k = 0; k < 16; ++k) {
      const float4 a = *(const float4*)(&As[k][ty << 2]);
      const float4 b = *(const float4*)(&Bs[k][tx << 2]);
      c[0][0] += a.x*b.x; c[0][1] += a.x*b.y; c[0][2] += a.x*b.z; c[0][3] += a.x*b.w;
      c[1][0] += a.y*b.x; c[1][1] += a.y*b.y; c[1][2] += a.y*b.z; c[1][3] += a.y*b.w;
      c[2][0] += a.z*b.x; c[2][1] += a.z*b.y; c[2][2] += a.z*b.z; c[2][3] += a.z*b.w;
      c[3][0] += a.w*b.x; c[3][1] += a.w*b.y; c[3][2] += a.w*b.z; c[3][3] += a.w*b.w;
    }
    __syncthreads();
  }
  const int n = n0 + (tx << 2);
  const float4 bb = *(const float4*)(bias + n);
#pragma unroll
  for (int i = 0; i < 4; ++i) {
    const int m = m0 + (ty << 2) + i;
    if (m >= M) break;
    float4 v = make_float4(c[i][0] + bb.x, c[i][1] + bb.y,
                           c[i][2] + bb.z, c[i][3] + bb.w);
    if (flags & GF_RELU) {
      v.x = fmaxf(v.x, 0.f); v.y = fmaxf(v.y, 0.f);
      v.z = fmaxf(v.z, 0.f); v.w = fmaxf(v.w, 0.f);
    }
    *(float4*)(out + (size_t)m * N + n) = v;
  }
}

// ---------------------------------------------------------------------------
// Attention scores from bf16 qkv: sc[bh][t][s] = q[t].k[s]/16, -inf s>t.
// ---------------------------------------------------------------------------
__global__ __launch_bounds__(256)
void attn_scores(const ushort_t* __restrict__ qkv, float* __restrict__ sc)
{
  const int bh = blockIdx.z;
  const int b = bh >> 2, h = bh & 3;
  const int t0 = blockIdx.y << 5;
  const int s0 = blockIdx.x << 6;
  if (s0 > t0 + 31) return;
  __shared__ float Qs[16][36];
  __shared__ float Ks[16][68];
  const int tx = threadIdx.x, ty = threadIdx.y;
  const int tid = (ty << 4) + tx;
  const int qr = tid >> 3;
  const int qc = (tid & 7) << 1;
  const int kr = tid >> 2;
  const int kc = (tid & 3) << 2;
  float c[2][4] = {};
  const ushort_t* qbase = qkv + (size_t)(b * T_) * (3 * D_) + h * DH_;
  const ushort_t* kbase = qbase + D_;
  for (int k0 = 0; k0 < DH_; k0 += 16) {
    const uint_t qv = *(const uint_t*)(qbase + (size_t)(t0 + qr) * (3 * D_) + k0 + qc);
    const uint2 kv = *(const uint2*)(kbase + (size_t)(s0 + kr) * (3 * D_) + k0 + kc);
    Qs[qc + 0][qr] = __uint_as_float(qv << 16);
    Qs[qc + 1][qr] = __uint_as_float(qv & 0xffff0000u);
    Ks[kc + 0][kr] = __uint_as_float(kv.x << 16);
    Ks[kc + 1][kr] = __uint_as_float(kv.x & 0xffff0000u);
    Ks[kc + 2][kr] = __uint_as_float(kv.y << 16);
    Ks[kc + 3][kr] = __uint_as_float(kv.y & 0xffff0000u);
    __syncthreads();
#pragma unroll
    for (int k = 0; k < 16; ++k) {
      const float a0 = Qs[k][(ty << 1) + 0];
      const float a1 = Qs[k][(ty << 1) + 1];
      const float4 bv = *(const float4*)(&Ks[k][tx << 2]);
      c[0][0] += a0*bv.x; c[0][1] += a0*bv.y; c[0][2] += a0*bv.z; c[0][3] += a0*bv.w;
      c[1][0] += a1*bv.x; c[1][1] += a1*bv.y; c[1][2] += a1*bv.z; c[1][3] += a1*bv.w;
    }
    __syncthreads();
  }
  float* scb = sc + (size_t)bh * T_ * T_;
#pragma unroll
  for (int i = 0; i < 2; ++i) {
    const int t = t0 + (ty << 1) + i;
#pragma unroll
    for (int j = 0; j < 4; ++j) {
      const int s = s0 + (tx << 2) + j;
      float v = c[i][j] * 0.0625f;
      if (s > t) v = -INFINITY;
      scb[(size_t)t * T_ + s] = v;
    }
  }
}

// ---------------------------------------------------------------------------
// Row softmax over [0, 64*(t/64+1)).
// ---------------------------------------------------------------------------
__global__ __launch_bounds__(256)
void softmax_rows(float* __restrict__ sc)
{
  const int row = blockIdx.x;
  const int t = row & (T_ - 1);
  const int bound = ((t >> 6) + 1) << 6;
  float* p = sc + (size_t)row * T_;
  const int tid = threadIdx.x;
  const int wave = tid >> 6, lane = tid & 63;
  float v0 = (tid < bound) ? p[tid] : -INFINITY;
  float v1 = (tid + 256 < bound) ? p[tid + 256] : -INFINITY;
  float m = fmaxf(v0, v1);
  for (int off = 32; off; off >>= 1) m = fmaxf(m, __shfl_down(m, off, 64));
  __shared__ float wm[4];
  __shared__ float wsum[4];
  if (!lane) wm[wave] = m;
  __syncthreads();
  m = fmaxf(fmaxf(wm[0], wm[1]), fmaxf(wm[2], wm[3]));
  float e0 = (tid < bound) ? __expf(v0 - m) : 0.f;
  float e1 = (tid + 256 < bound) ? __expf(v1 - m) : 0.f;
  float s = e0 + e1;
  for (int off = 32; off; off >>= 1) s += __shfl_down(s, off, 64);
  if (!lane) wsum[wave] = s;
  __syncthreads();
  s = wsum[0] + wsum[1] + wsum[2] + wsum[3];
  const float inv = 1.f / s;
  if (tid < bound) p[tid] = e0 * inv;
  if (tid + 256 < bound) p[tid + 256] = e1 * inv;
}

// ---------------------------------------------------------------------------
// P.V with bf16 V, bf16 output.
// ---------------------------------------------------------------------------
__global__ __launch_bounds__(256)
void attn_pv(const float* __restrict__ sc, const ushort_t* __restrict__ qkv,
             ushort_t* __restrict__ ao)
{
  const int bh = blockIdx.z, b = bh >> 2, h = bh & 3;
  const int t0 = blockIdx.y << 5;
  const int d0 = blockIdx.x << 6;
  const int kmax = ((t0 >> 6) + 1) << 6;
  __shared__ float Ps[16][36];
  __shared__ float Vs[16][68];
  const int tx = threadIdx.x, ty = threadIdx.y;
  const int tid = (ty << 4) + tx;
  const int pr = tid >> 3;
  const int pc = (tid & 7) << 1;
  const int vr = tid >> 4;
  const int vc = (tid & 15) << 2;
  float c[2][4] = {};
  const float* scb = sc + (size_t)bh * T_ * T_;
  const ushort_t* vbase = qkv + (size_t)(b * T_) * (3 * D_) + 2 * D_ + h * DH_;
  for (int k0 = 0; k0 < kmax; k0 += 16) {
    const float2 pv = *(const float2*)(scb + (size_t)(t0 + pr) * T_ + k0 + pc);
    const uint2 vv = *(const uint2*)(vbase + (size_t)(k0 + vr) * (3 * D_) + d0 + vc);
    Ps[pc + 0][pr] = pv.x; Ps[pc + 1][pr] = pv.y;
    Vs[vr][vc + 0] = __uint_as_float(vv.x << 16);
    Vs[vr][vc + 1] = __uint_as_float(vv.x & 0xffff0000u);
    Vs[vr][vc + 2] = __uint_as_float(vv.y << 16);
    Vs[vr][vc + 3] = __uint_as_float(vv.y & 0xffff0000u);
    __syncthreads();
#pragma unroll
    for (int k = 0; k < 16; ++k) {
      const float a0 = Ps[k][(ty << 1) + 0];
      const float a1 = Ps[k][(ty << 1) + 1];
      const float4 bv = *(const float4*)(&Vs[k][tx << 2]);
      c[0][0] += a0*bv.x; c[0][1] += a0*bv.y; c[0][2] += a0*bv.z; c[0][3] += a0*bv.w;
      c[1][0] += a1*bv.x; c[1][1] += a1*bv.y; c[1][2] += a1*bv.z; c[1][3] += a1*bv.w;
    }
    __syncthreads();
  }
  ushort_t* aob = ao + (size_t)(b * T_ + t0) * D_ + h * DH_ + d0;
#pragma unroll
  for (int i = 0; i < 2; ++i) {
    ushort4 o;
    o.x = f2bf(c[i][0]); o.y = f2bf(c[i][1]);
    o.z = f2bf(c[i][2]); o.w = f2bf(c[i][3]);
    *(ushort4*)(aob + (size_t)((ty << 1) + i) * D_ + (tx << 2)) = o;
  }
}

// ---------------------------------------------------------------------------
// LayerNorm over D=1024; fp32 in, bf16 out (residual stream carried in bf16).
// ---------------------------------------------------------------------------
__global__ __launch_bounds__(256)
void layernorm_k(const float* __restrict__ in, const float* __restrict__ g,
                 const float* __restrict__ bta, ushort_t* __restrict__ outb)
{
  const int row = blockIdx.x;
  const int tid = threadIdx.x;
  const int wave = tid >> 6, lane = tid & 63;
  const float4 v = *(const float4*)(in + (size_t)row * D_ + (tid << 2));
  float s = v.x + v.y + v.z + v.w;
  float ss = v.x*v.x + v.y*v.y + v.z*v.z + v.w*v.w;
  for (int off = 32; off; off >>= 1) {
    s  += __shfl_down(s, off, 64);
    ss += __shfl_down(ss, off, 64);
  }
  __shared__ float ra[4], rb[4];
  if (!lane) { ra[wave] = s; rb[wave] = ss; }
  __syncthreads();
  s  = ra[0] + ra[1] + ra[2] + ra[3];
  ss = rb[0] + rb[1] + rb[2] + rb[3];
  const float mu = s * (1.f / (float)D_);
  const float var = ss * (1.f / (float)D_) - mu * mu;
  const float rstd = rsqrtf(var + EPS_);
  const float4 gv = *(const float4*)(g + (tid << 2));
  const float4 bv = *(const float4*)(bta + (tid << 2));
  ushort4 o;
  o.x = f2bf((v.x - mu) * rstd * gv.x + bv.x);
  o.y = f2bf((v.y - mu) * rstd * gv.y + bv.y);
  o.z = f2bf((v.z - mu) * rstd * gv.z + bv.z);
  o.w = f2bf((v.w - mu) * rstd * gv.w + bv.w);
  *(ushort4*)(outb + (size_t)row * D_ + (tid << 2)) = o;
}

// ---------------------------------------------------------------------------
// Head layer 2 + sigmoid (fp32 hidden).
// ---------------------------------------------------------------------------
__global__ __launch_bounds__(256)
void head2_sigmoid(const float* __restrict__ h1, const float* __restrict__ w2,
                   const float* __restrict__ b2, float* __restrict__ sout)
{
  const int tid = threadIdx.x;
  const int wave = tid >> 6, lane = tid & 63;
  const int m = (blockIdx.x << 2) + wave;
  const float* hr = h1 + (size_t)m * 512;
  float s = 0.f;
#pragma unroll
  for (int i = 0; i < 8; ++i) s += hr[i * 64 + lane] * w2[i * 64 + lane];
  for (int off = 32; off; off >>= 1) s += __shfl_down(s, off, 64);
  if (!lane) sout[m] = 1.f / (1.f + expf(-(s + b2[0])));
}

__global__ __launch_bounds__(256)
void select_worst(const float* __restrict__ s, int* __restrict__ w,
                  int* __restrict__ hasbad, int* __restrict__ counts)
{
  const int b = blockIdx.x, tid = threadIdx.x;
  const float* sr = s + b * T_;
  float bv = INFINITY; int bi = 0;
  for (int i = tid; i < T_; i += 256) {
    const float v = sr[i];
    const float cand = (v < THRESH_) ? v : INFINITY;
    if (cand < bv || (cand == bv && i < bi)) { bv = cand; bi = i; }
  }
  __shared__ float rv[256];
  __shared__ int ri[256];
  rv[tid] = bv; ri[tid] = bi;
  __syncthreads();
  for (int str = 128; str; str >>= 1) {
    if (tid < str) {
      const float v2 = rv[tid + str]; const int i2 = ri[tid + str];
      if (v2 < rv[tid] || (v2 == rv[tid] && i2 < ri[tid])) { rv[tid] = v2; ri[tid] = i2; }
    }
    __syncthreads();
  }
  if (!tid) {
    const int bad = (rv[0] < INFINITY) ? 1 : 0;
    w[b] = ri[0];
    hasbad[b] = bad;
    counts[b] += bad;
  }
}

__global__ __launch_bounds__(256)
void gather_cinp(const float* __restrict__ corr, const int* __restrict__ w,
                 float* __restrict__ cinp)
{
  const int b = blockIdx.x, tid = threadIdx.x;
  const int wi = w[b];
  const float* base = corr + (size_t)b * T_ * D_;
  const int nv = 3 - (wi == 0 ? 1 : 0) - (wi == T_ - 1 ? 1 : 0);
  const float inv = 1.f / (float)nv;
  const int d = tid << 2;
  const float4 cur = *(const float4*)(base + (size_t)wi * D_ + d);
  float4 acc = cur;
  if (wi > 0) {
    const float4 p = *(const float4*)(base + (size_t)(wi - 1) * D_ + d);
    acc.x += p.x; acc.y += p.y; acc.z += p.z; acc.w += p.w;
  }
  if (wi < T_ - 1) {
    const float4 p = *(const float4*)(base + (size_t)(wi + 1) * D_ + d);
    acc.x += p.x; acc.y += p.y; acc.z += p.z; acc.w += p.w;
  }
  acc.x *= inv; acc.y *= inv; acc.z *= inv; acc.w *= inv;
  *(float4*)(cinp + (size_t)b * (2 * D_) + d) = cur;
  *(float4*)(cinp + (size_t)b * (2 * D_) + D_ + d) = acc;
}

__global__ __launch_bounds__(256)
void apply_corr(float* __restrict__ corr, const int* __restrict__ w,
                const int* __restrict__ hasbad, const float* __restrict__ ns)
{
  const int b = blockIdx.x;
  if (!hasbad[b]) return;
  const int wi = w[b], tid = threadIdx.x;
  *(float4*)(corr + (size_t)(b * T_ + wi) * D_ + (tid << 2)) =
      *(const float4*)(ns + (size_t)b * D_ + (tid << 2));
}

__global__ __launch_bounds__(256)
void init_copy(const float* __restrict__ chain, float* __restrict__ corr,
               int* __restrict__ counts)
{
  const size_t i = ((size_t)blockIdx.x * 256 + threadIdx.x) << 2;
  *(float4*)(corr + i) = *(const float4*)(chain + i);
  if (blockIdx.x == 0 && threadIdx.x < B_) counts[threadIdx.x] = 0;
}

__global__ __launch_bounds__(256)
void finalize_k(const float* __restrict__ s0, const float* __restrict__ fs,
                const int* __restrict__ cnt, float* __restrict__ oc,
                float* __restrict__ oi)
{
  const int b = blockIdx.x, tid = threadIdx.x;
  const int wave = tid >> 6, lane = tid & 63;
  float a = s0[b * T_ + tid] + s0[b * T_ + tid + 256];
  float c = fs[b * T_ + tid] + fs[b * T_ + tid + 256];
  for (int off = 32; off; off >>= 1) {
    a += __shfl_down(a, off, 64);
    c += __shfl_down(c, off, 64);
  }
  __shared__ float ra[4], rc[4];
  if (!lane) { ra[wave] = a; rc[wave] = c; }
  __syncthreads();
  if (!tid) {
    const float as = ra[0] + ra[1] + ra[2] + ra[3];
    const float cs = rc[0] + rc[1] + rc[2] + rc[3];
    oc[b] = (float)cnt[b];
    oi[b] = (cs > as) ? 1.f : 0.f;
  }
}

// ---------------------------------------------------------------------------
extern "C" void kernel_launch(void* const* d_in, const int* in_sizes, int n_in,
                              void* d_out, int out_size, void* d_ws, size_t ws_size,
                              hipStream_t stream)
{
  const float* chain  = (const float*)d_in[0];
  const float* Wqkv   = (const float*)d_in[1];
  const float* bqkv   = (const float*)d_in[2];
  const float* Wo     = (const float*)d_in[3];
  const float* bo     = (const float*)d_in[4];
  const float* ln1g   = (const float*)d_in[5];
  const float* ln1b   = (const float*)d_in[6];
  const float* W1     = (const float*)d_in[7];
  const float* b1     = (const float*)d_in[8];
  const float* W2     = (const float*)d_in[9];
  const float* b2     = (const float*)d_in[10];
  const float* ln2g   = (const float*)d_in[11];
  const float* ln2b   = (const float*)d_in[12];
  const float* rhW1   = (const float*)d_in[13];
  const float* rhb1   = (const float*)d_in[14];
  const float* rhW2   = (const float*)d_in[15];
  const float* rhb2   = (const float*)d_in[16];
  const float* corW1  = (const float*)d_in[17];
  const float* corb1  = (const float*)d_in[18];
  const float* corW2  = (const float*)d_in[19];
  const float* corb2  = (const float*)d_in[20];

  float* ws = (float*)d_ws;
  // ---- workspace layout (float offsets), live-range aliased ----
  // RegionB [0 .. 12,582,912): QKV16 bf16 (steps QKV..PV) / PRE f32 / E f32
  ushort_t* QKV16 = (ushort_t*)ws;
  float*    PRE   = ws;
  float*    E     = ws;
  // RegionA [12,582,912 .. 29,360,128): SC f32 (attn) / Hb bf16 (FF hidden)
  float*    SC    = ws + 12582912;
  ushort_t* Hb    = (ushort_t*)SC;
  // Xb bf16 activations [29,360,128 .. 33,554,432)
  ushort_t* Xb    = (ushort_t*)(ws + 29360128);
  // AOb bf16 / HH f32 / run_iter scratch [33,554,432 .. 37,748,736)
  ushort_t* AOb   = (ushort_t*)(ws + 33554432);
  float*    HH    = ws + 33554432;
  float*    cinp  = ws + 33554432;       // run_iter only (AOb/HH dead then)
  float*    corrH = cinp + 32768;
  float*    nstep = corrH + 32768;
  // bf16 weights blob [37,748,736 .. 50,593,792)
  ushort_t* W16     = (ushort_t*)(ws + 37748736);
  ushort_t* Wqkv16  = W16;               //  6,291,456
  ushort_t* Wo16    = W16 + 6291456;     //  2,097,152
  ushort_t* W116    = W16 + 8388608;     //  8,388,608
  ushort_t* W216    = W16 + 16777216;    //  8,388,608
  ushort_t* rhW116  = W16 + 25165824;    //    524,288
  // persistent small buffers
  float* s0buf = ws + 50593792;          // 8192
  float* sbuf  = s0buf + 8192;           // 8192
  int* wbuf   = (int*)(sbuf + 8192);
  int* badbuf = wbuf + 16;
  int* cntbuf = badbuf + 16;

  float* outCorr   = (float*)d_out;
  float* outCounts = outCorr + 8388608;
  float* outFS     = outCounts + 16;
  float* outImpr   = outFS + 8192;

  const dim3 blk2(16, 16);
  const dim3 blk1(256);

  // ---- weight conversion (once per launch; graph-safe, same work each call)
  cvt_f32_bf16<<<dim3(6144), blk1, 0, stream>>>(Wqkv, Wqkv16, 6291456);
  cvt_f32_bf16<<<dim3(2048), blk1, 0, stream>>>(Wo,   Wo16,   2097152);
  cvt_f32_bf16<<<dim3(8192), blk1, 0, stream>>>(W1,   W116,   8388608);
  cvt_f32_bf16<<<dim3(8192), blk1, 0, stream>>>(W2,   W216,   8388608);
  cvt_f32_bf16<<<dim3(512),  blk1, 0, stream>>>(rhW1, rhW116, 524288);

  auto run_prm = [&](const float* xin, float* scoresOut) {
    cvt_f32_bf16<<<dim3(8192), blk1, 0, stream>>>(xin, Xb, 8388608);
    for (int l = 0; l < 2; ++l) {
      gemm_bf16<<<dim3(24, 64), blk1, 0, stream>>>(
          Xb, Wqkv16 + (size_t)l * 3 * D_ * D_, bqkv + (size_t)l * 3 * D_,
          nullptr, nullptr, QKV16, M_, 3 * D_, D_, GF_OUTBF16);
      attn_scores<<<dim3(8, 16, 64), blk2, 0, stream>>>(QKV16, SC);
      softmax_rows<<<dim3(64 * T_), blk1, 0, stream>>>(SC);
      attn_pv<<<dim3(4, 16, 64), blk2, 0, stream>>>(SC, QKV16, AOb);
      gemm_bf16<<<dim3(8, 64), blk1, 0, stream>>>(
          AOb, Wo16 + (size_t)l * D_ * D_, bo + (size_t)l * D_,
          Xb, PRE, nullptr, M_, D_, D_, GF_RES);
      layernorm_k<<<dim3(M_), blk1, 0, stream>>>(PRE, ln1g + l * D_,
                                                 ln1b + l * D_, Xb);
      gemm_bf16<<<dim3(32, 64), blk1, 0, stream>>>(
          Xb, W116 + (size_t)l * FF_ * D_, b1 + (size_t)l * FF_,
          nullptr, nullptr, Hb, M_, FF_, D_, GF_RELU | GF_OUTBF16);
      gemm_bf16<<<dim3(8, 64), blk1, 0, stream>>>(
          Hb, W216 + (size_t)l * D_ * FF_, b2 + (size_t)l * D_,
          Xb, E, nullptr, M_, D_, FF_, GF_RES);
      layernorm_k<<<dim3(M_), blk1, 0, stream>>>(E, ln2g + l * D_,
                                                 ln2b + l * D_, Xb);
    }
    gemm_bf16<<<dim3(4, 64), blk1, 0, stream>>>(
        Xb, rhW116, rhb1, nullptr, HH, nullptr, M_, 512, D_, GF_RELU);
    head2_sigmoid<<<dim3(M_ / 4), blk1, 0, stream>>>(HH, rhW2, rhb2, scoresOut);
  };

  auto run_iter = [&](const float* sPtr) {
    select_worst<<<dim3(B_), blk1, 0, stream>>>(sPtr, wbuf, badbuf, cntbuf);
    gather_cinp<<<dim3(B_), blk1, 0, stream>>>(outCorr, wbuf, cinp);
    gemm_bt<<<dim3(32, 1), blk2, 0, stream>>>(cinp, corW1, corb1, corrH,
                                              B_, 2 * D_, 2 * D_, GF_RELU);
    gemm_bt<<<dim3(16, 1), blk2, 0, stream>>>(corrH, corW2, corb2, nstep,
                                              B_, D_, 2 * D_, 0);
    apply_corr<<<dim3(B_), blk1, 0, stream>>>(outCorr, wbuf, badbuf, nstep);
  };

  init_copy<<<dim3(8192), blk1, 0, stream>>>(chain, outCorr, cntbuf);

  // prm #1 on chain; iteration 1 reuses scores0 (corrected == chain there).
  run_prm(chain, s0buf);
  run_iter(s0buf);
  run_prm(outCorr, sbuf);
  run_iter(sbuf);
  run_prm(outCorr, sbuf);
  run_iter(sbuf);
  run_prm(outCorr, outFS);
  finalize_k<<<dim3(B_), blk1, 0, stream>>>(s0buf, outFS, cntbuf,
                                            outCounts, outImpr);
  (void)in_sizes; (void)n_in; (void)out_size; (void)ws_size;
}

// Round 5
// 5236.761 us; speedup vs baseline: 5.7354x; 1.2439x over previous
//
#include <hip/hip_runtime.h>
#include <math.h>

#define B_ 16
#define T_ 512
#define D_ 1024
#define H_ 4
#define DH_ 256
#define FF_ 4096
#define M_ (B_*T_)
#define THRESH_ 0.3f
#define EPS_ 1e-5f

#define GF_RELU 1
#define GF_RES  2
#define GF_OUTBF16 4
#define GF_SPLITV 8

typedef unsigned short ushort_t;
typedef unsigned int uint_t;

using s16x8 = __attribute__((ext_vector_type(8))) short;
using f32x4 = __attribute__((ext_vector_type(4))) float;

typedef const __attribute__((address_space(1))) void* gas_ptr;
typedef __attribute__((address_space(3))) void* lds_ptr;

static __device__ __forceinline__ ushort_t f2bf(float f) {
  uint_t x = __float_as_uint(f);
  return (ushort_t)((x + 0x7FFFu + ((x >> 16) & 1u)) >> 16);  // RNE
}
static __device__ __forceinline__ float bf2f(ushort_t u) {
  return __uint_as_float(((uint_t)u) << 16);
}

// ---------------------------------------------------------------------------
__global__ __launch_bounds__(256)
void cvt_f32_bf16(const float* __restrict__ in, ushort_t* __restrict__ out, int n)
{
  const int i = (blockIdx.x * 256 + threadIdx.x) << 2;
  if (i >= n) return;
  const float4 v = *(const float4*)(in + i);
  ushort4 o;
  o.x = f2bf(v.x); o.y = f2bf(v.y); o.z = f2bf(v.z); o.w = f2bf(v.w);
  *(ushort4*)(out + i) = o;
}

// ---------------------------------------------------------------------------
// bf16 MFMA GEMM: out[M,N] = A[M,K]*Bt[N,K]^T + bias (+res)(relu).
// GF_SPLITV: cols >= 2048 (V part of QKV) go to vt transposed-chunked:
// Vtg[bh][t>>5][d][t&31].
// ---------------------------------------------------------------------------
__global__ __launch_bounds__(256)
void gemm_bf16(const ushort_t* __restrict__ A, const ushort_t* __restrict__ Bt,
               const float* __restrict__ bias, const ushort_t* __restrict__ res,
               float* __restrict__ outF, ushort_t* __restrict__ outB,
               ushort_t* __restrict__ vt,
               int M, int N, int K, int flags)
{
  __shared__ ushort_t As[128 * 32];
  __shared__ ushort_t Bs[128 * 32];
  const int n0 = blockIdx.x << 7;
  const int m0 = blockIdx.y << 7;
  const int tid = threadIdx.x;
  const int wv = tid >> 6, ln = tid & 63;
  const int wm = (wv >> 1) << 6;
  const int wn = (wv & 1) << 6;
  const int lrow = ln & 15, quad = ln >> 4;

  f32x4 acc[4][4] = {};

  const ushort_t* ga = A + (size_t)(m0 + wv * 16 + (ln >> 2)) * K + ((ln & 3) << 3);
  const ushort_t* gb = Bt + (size_t)(n0 + wv * 16 + (ln >> 2)) * K + ((ln & 3) << 3);
  ushort_t* lA = &As[wv * 512];
  ushort_t* lB = &Bs[wv * 512];

  for (int k0 = 0; k0 < K; k0 += 32) {
    __builtin_amdgcn_global_load_lds((gas_ptr)(const void*)ga,
                                     (lds_ptr)(void*)lA, 16, 0, 0);
    __builtin_amdgcn_global_load_lds((gas_ptr)(const void*)(ga + (size_t)64 * K),
                                     (lds_ptr)(void*)(lA + 2048), 16, 0, 0);
    __builtin_amdgcn_global_load_lds((gas_ptr)(const void*)gb,
                                     (lds_ptr)(void*)lB, 16, 0, 0);
    __builtin_amdgcn_global_load_lds((gas_ptr)(const void*)(gb + (size_t)64 * K),
                                     (lds_ptr)(void*)(lB + 2048), 16, 0, 0);
    ga += 32; gb += 32;
    __syncthreads();
    s16x8 af[4], bfr[4];
#pragma unroll
    for (int i = 0; i < 4; ++i)
      af[i] = *(const s16x8*)(&As[(wm + i * 16 + lrow) * 32 + quad * 8]);
#pragma unroll
    for (int j = 0; j < 4; ++j)
      bfr[j] = *(const s16x8*)(&Bs[(wn + j * 16 + lrow) * 32 + quad * 8]);
#pragma unroll
    for (int i = 0; i < 4; ++i)
#pragma unroll
      for (int j = 0; j < 4; ++j)
        acc[i][j] = __builtin_amdgcn_mfma_f32_16x16x32_bf16(af[i], bfr[j],
                                                            acc[i][j], 0, 0, 0);
    __syncthreads();
  }

#pragma unroll
  for (int i = 0; i < 4; ++i) {
    const int row0 = m0 + wm + i * 16 + quad * 4;
#pragma unroll
    for (int j = 0; j < 4; ++j) {
      const int c = n0 + wn + j * 16 + lrow;
      const float bb = bias[c];
      const bool isV = (flags & GF_SPLITV) && (c >= 2048);
#pragma unroll
      for (int r = 0; r < 4; ++r) {
        float v = acc[i][j][r] + bb;
        const int m = row0 + r;
        const size_t idx = (size_t)m * N + c;
        if (flags & GF_RES) v += bf2f(res[idx]);
        if (flags & GF_RELU) v = fmaxf(v, 0.f);
        if (isV) {
          const int t = m & 511, bb2 = m >> 9;
          const int hh = (c - 2048) >> 8, d = (c - 2048) & 255;
          vt[(((size_t)(bb2 * 4 + hh) * 16 + (t >> 5)) << 13) + d * 32 + (t & 31)]
              = f2bf(v);
        } else if (flags & GF_OUTBF16) outB[idx] = f2bf(v);
        else outF[idx] = v;
      }
    }
  }
}

// ---------------------------------------------------------------------------
// Fused flash attention. Q frags in registers, K/V double-buffered in LDS via
// global_load_lds, online softmax, MFMA QK^T & PV. P carried as hi+lo bf16.
// ---------------------------------------------------------------------------
__global__ __launch_bounds__(256)
void flash_attn(const ushort_t* __restrict__ qkv, const ushort_t* __restrict__ vtg,
                ushort_t* __restrict__ ao)
{
  __shared__ ushort_t Ks[2][8 * 64 * 32];     // [buf][kc*64+row][32]
  __shared__ ushort_t Vs[2][2 * 256 * 32];    // [buf][c*256+d][32]
  __shared__ ushort_t Ph[4][16][80];          // wave-private P hi
  __shared__ ushort_t Pl[4][16][80];          // wave-private P lo
  const int qt = (int)gridDim.x - 1 - blockIdx.x;   // heavy-first
  const int t0 = qt << 6;
  const int bh = blockIdx.y;
  const int b = bh >> 2, h = bh & 3;
  const int nIter = qt + 1;
  const int tid = threadIdx.x;
  const int wv = tid >> 6, ln = tid & 63;
  const int lrow = ln & 15, quad = ln >> 4;

  s16x8 qf[8];
  {
    const ushort_t* qrow = qkv + (size_t)(b * T_ + t0 + wv * 16 + lrow) * 3072
                           + h * 256 + quad * 8;
#pragma unroll
    for (int kc = 0; kc < 8; ++kc)
      qf[kc] = *(const s16x8*)(qrow + kc * 32);
  }

  const ushort_t* kg = qkv + (size_t)(b * T_) * 3072 + 1024 + h * 256;
  const ushort_t* vg = vtg + (size_t)bh * 131072;

  auto issue_k = [&](int i, int buf) {
#pragma unroll
    for (int iss = 0; iss < 8; ++iss) {
      const int R = 128 * wv + 16 * iss + (ln >> 2);
      const ushort_t* g = kg + (size_t)(64 * i + (R & 63)) * 3072
                          + (R >> 6) * 32 + ((ln & 3) << 3);
      ushort_t* l = &Ks[buf][(128 * wv + 16 * iss) * 32];
      __builtin_amdgcn_global_load_lds((gas_ptr)(const void*)g,
                                       (lds_ptr)(void*)l, 16, 0, 0);
    }
  };
  auto issue_v = [&](int i, int buf) {
#pragma unroll
    for (int iss = 0; iss < 8; ++iss) {   // 8 x 512 = full 4096/wave (fix)
      const ushort_t* g = vg + (size_t)i * 16384 + wv * 4096 + iss * 512 + ln * 8;
      ushort_t* l = &Vs[buf][wv * 4096 + iss * 512];
      __builtin_amdgcn_global_load_lds((gas_ptr)(const void*)g,
                                       (lds_ptr)(void*)l, 16, 0, 0);
    }
  };

  issue_k(0, 0);
  issue_v(0, 0);

  f32x4 o[16] = {};
  float Mx[4], L[4];
#pragma unroll
  for (int r = 0; r < 4; ++r) { Mx[r] = -3.0e38f; L[r] = 0.f; }

  for (int it = 0; it < nIter; ++it) {
    const int buf = it & 1;
    __syncthreads();   // vmcnt(0)+barrier: tile `it` fully resident
    if (it + 1 < nIter) { issue_k(it + 1, buf ^ 1); issue_v(it + 1, buf ^ 1); }

    // S = Q.K^T
    f32x4 s[4] = {};
#pragma unroll
    for (int kc = 0; kc < 8; ++kc)
#pragma unroll
      for (int j = 0; j < 4; ++j) {
        const s16x8 bfv = *(const s16x8*)(&Ks[buf][(kc * 64 + 16 * j + lrow) * 32
                                                   + quad * 8]);
        s[j] = __builtin_amdgcn_mfma_f32_16x16x32_bf16(qf[kc], bfv, s[j], 0, 0, 0);
      }

    const bool diag = (it == qt);
#pragma unroll
    for (int j = 0; j < 4; ++j)
#pragma unroll
      for (int r = 0; r < 4; ++r) {
        float v = s[j][r] * 0.0625f;
        if (diag && (16 * j + lrow > 16 * wv + quad * 4 + r)) v = -INFINITY;
        s[j][r] = v;
      }

    // online softmax (row = quad*4+r, spread over the quad's 16 lanes)
    float alpha[4];
#pragma unroll
    for (int r = 0; r < 4; ++r) {
      float m = fmaxf(fmaxf(s[0][r], s[1][r]), fmaxf(s[2][r], s[3][r]));
      m = fmaxf(m, __shfl_xor(m, 1));
      m = fmaxf(m, __shfl_xor(m, 2));
      m = fmaxf(m, __shfl_xor(m, 4));
      m = fmaxf(m, __shfl_xor(m, 8));
      const float mn = fmaxf(Mx[r], m);
      alpha[r] = __expf(Mx[r] - mn);
      Mx[r] = mn;
      float l = 0.f;
#pragma unroll
      for (int j = 0; j < 4; ++j) {
        const float p = __expf(s[j][r] - mn);
        s[j][r] = p;
        l += p;
      }
      l += __shfl_xor(l, 1);
      l += __shfl_xor(l, 2);
      l += __shfl_xor(l, 4);
      l += __shfl_xor(l, 8);
      L[r] = L[r] * alpha[r] + l;
    }

    // P -> LDS as hi+lo bf16 pair (C-layout -> A-layout); rescale O
#pragma unroll
    for (int j = 0; j < 4; ++j)
#pragma unroll
      for (int r = 0; r < 4; ++r) {
        const float p = s[j][r];
        const ushort_t hi = f2bf(p);
        Ph[wv][quad * 4 + r][16 * j + lrow] = hi;
        Pl[wv][quad * 4 + r][16 * j + lrow] = f2bf(p - bf2f(hi));
      }
#pragma unroll
    for (int jd = 0; jd < 16; ++jd)
#pragma unroll
      for (int r = 0; r < 4; ++r)
        o[jd][r] *= alpha[r];

    // O += (P_hi + P_lo).V
#pragma unroll
    for (int c = 0; c < 2; ++c) {
      const s16x8 ph = *(const s16x8*)(&Ph[wv][lrow][32 * c + quad * 8]);
      const s16x8 pl = *(const s16x8*)(&Pl[wv][lrow][32 * c + quad * 8]);
#pragma unroll
      for (int jd = 0; jd < 16; ++jd) {
        const s16x8 vb = *(const s16x8*)(&Vs[buf][(c * 256 + 16 * jd + lrow) * 32
                                                  + quad * 8]);
        o[jd] = __builtin_amdgcn_mfma_f32_16x16x32_bf16(ph, vb, o[jd], 0, 0, 0);
        o[jd] = __builtin_amdgcn_mfma_f32_16x16x32_bf16(pl, vb, o[jd], 0, 0, 0);
      }
    }
  }

  float inv[4];
#pragma unroll
  for (int r = 0; r < 4; ++r) inv[r] = 1.f / L[r];
  ushort_t* aob = ao + (size_t)(b * T_ + t0 + 16 * wv + quad * 4) * 1024 + h * 256;
#pragma unroll
  for (int jd = 0; jd < 16; ++jd)
#pragma unroll
    for (int r = 0; r < 4; ++r)
      aob[(size_t)r * 1024 + 16 * jd + lrow] = f2bf(o[jd][r] * inv[r]);
}

// ---------------------------------------------------------------------------
// fp32 tiled GEMM (tiny correction MLP only, M=16).
// ---------------------------------------------------------------------------
__global__ __launch_bounds__(256)
void gemm_bt(const float* __restrict__ A, const float* __restrict__ Bt,
             const float* __restrict__ bias, float* __restrict__ out,
             int M, int N, int K, int flags)
{
  __shared__ float As[16][68];
  __shared__ float Bs[16][68];
  const int n0 = blockIdx.x << 6;
  const int m0 = blockIdx.y << 6;
  const int tx = threadIdx.x, ty = threadIdx.y;
  const int tid = (ty << 4) + tx;
  const int lr = tid >> 2;
  const int lc = (tid & 3) << 2;
  float c[4][4] = {};
  for (int k0 = 0; k0 < K; k0 += 16) {
    float4 av = make_float4(0.f, 0.f, 0.f, 0.f);
    if (m0 + lr < M)
      av = *(const float4*)(A + (size_t)(m0 + lr) * K + k0 + lc);
    const float4 bv = *(const float4*)(Bt + (size_t)(n0 + lr) * K + k0 + lc);
    As[lc + 0][lr] = av.x; As[lc + 1][lr] = av.y;
    As[lc + 2][lr] = av.z; As[lc + 3][lr] = av.w;
    Bs[lc + 0][lr] = bv.x; Bs[lc + 1][lr] = bv.y;
    Bs[lc + 2][lr] = bv.z; Bs[lc + 3][lr] = bv.w;
    __syncthreads();
#pragma unroll
    for (int k = 0; k < 16; ++k) {
      const float4 a = *(const float4*)(&As[k][ty << 2]);
      const float4 b = *(const float4*)(&Bs[k][tx << 2]);
      c[0][0] += a.x*b.x; c[0][1] += a.x*b.y; c[0][2] += a.x*b.z; c[0][3] += a.x*b.w;
      c[1][0] += a.y*b.x; c[1][1] += a.y*b.y; c[1][2] += a.y*b.z; c[1][3] += a.y*b.w;
      c[2][0] += a.z*b.x; c[2][1] += a.z*b.y; c[2][2] += a.z*b.z; c[2][3] += a.z*b.w;
      c[3][0] += a.w*b.x; c[3][1] += a.w*b.y; c[3][2] += a.w*b.z; c[3][3] += a.w*b.w;
    }
    __syncthreads();
  }
  const int n = n0 + (tx << 2);
  const float4 bb = *(const float4*)(bias + n);
#pragma unroll
  for (int i = 0; i < 4; ++i) {
    const int m = m0 + (ty << 2) + i;
    if (m >= M) break;
    float4 v = make_float4(c[i][0] + bb.x, c[i][1] + bb.y,
                           c[i][2] + bb.z, c[i][3] + bb.w);
    if (flags & GF_RELU) {
      v.x = fmaxf(v.x, 0.f); v.y = fmaxf(v.y, 0.f);
      v.z = fmaxf(v.z, 0.f); v.w = fmaxf(v.w, 0.f);
    }
    *(float4*)(out + (size_t)m * N + n) = v;
  }
}

// ---------------------------------------------------------------------------
__global__ __launch_bounds__(256)
void layernorm_k(const float* __restrict__ in, const float* __restrict__ g,
                 const float* __restrict__ bta, ushort_t* __restrict__ outb)
{
  const int row = blockIdx.x;
  const int tid = threadIdx.x;
  const int wave = tid >> 6, lane = tid & 63;
  const float4 v = *(const float4*)(in + (size_t)row * D_ + (tid << 2));
  float s = v.x + v.y + v.z + v.w;
  float ss = v.x*v.x + v.y*v.y + v.z*v.z + v.w*v.w;
  for (int off = 32; off; off >>= 1) {
    s  += __shfl_down(s, off, 64);
    ss += __shfl_down(ss, off, 64);
  }
  __shared__ float ra[4], rb[4];
  if (!lane) { ra[wave] = s; rb[wave] = ss; }
  __syncthreads();
  s  = ra[0] + ra[1] + ra[2] + ra[3];
  ss = rb[0] + rb[1] + rb[2] + rb[3];
  const float mu = s * (1.f / (float)D_);
  const float var = ss * (1.f / (float)D_) - mu * mu;
  const float rstd = rsqrtf(var + EPS_);
  const float4 gv = *(const float4*)(g + (tid << 2));
  const float4 bv = *(const float4*)(bta + (tid << 2));
  ushort4 o;
  o.x = f2bf((v.x - mu) * rstd * gv.x + bv.x);
  o.y = f2bf((v.y - mu) * rstd * gv.y + bv.y);
  o.z = f2bf((v.z - mu) * rstd * gv.z + bv.z);
  o.w = f2bf((v.w - mu) * rstd * gv.w + bv.w);
  *(ushort4*)(outb + (size_t)row * D_ + (tid << 2)) = o;
}

__global__ __launch_bounds__(256)
void head2_sigmoid(const float* __restrict__ h1, const float* __restrict__ w2,
                   const float* __restrict__ b2, float* __restrict__ sout)
{
  const int tid = threadIdx.x;
  const int wave = tid >> 6, lane = tid & 63;
  const int m = (blockIdx.x << 2) + wave;
  const float* hr = h1 + (size_t)m * 512;
  float s = 0.f;
#pragma unroll
  for (int i = 0; i < 8; ++i) s += hr[i * 64 + lane] * w2[i * 64 + lane];
  for (int off = 32; off; off >>= 1) s += __shfl_down(s, off, 64);
  if (!lane) sout[m] = 1.f / (1.f + expf(-(s + b2[0])));
}

__global__ __launch_bounds__(256)
void select_worst(const float* __restrict__ s, int* __restrict__ w,
                  int* __restrict__ hasbad, int* __restrict__ counts)
{
  const int b = blockIdx.x, tid = threadIdx.x;
  const float* sr = s + b * T_;
  float bv = INFINITY; int bi = 0;
  for (int i = tid; i < T_; i += 256) {
    const float v = sr[i];
    const float cand = (v < THRESH_) ? v : INFINITY;
    if (cand < bv || (cand == bv && i < bi)) { bv = cand; bi = i; }
  }
  __shared__ float rv[256];
  __shared__ int ri[256];
  rv[tid] = bv; ri[tid] = bi;
  __syncthreads();
  for (int str = 128; str; str >>= 1) {
    if (tid < str) {
      const float v2 = rv[tid + str]; const int i2 = ri[tid + str];
      if (v2 < rv[tid] || (v2 == rv[tid] && i2 < ri[tid])) { rv[tid] = v2; ri[tid] = i2; }
    }
    __syncthreads();
  }
  if (!tid) {
    const int bad = (rv[0] < INFINITY) ? 1 : 0;
    w[b] = ri[0];
    hasbad[b] = bad;
    counts[b] += bad;
  }
}

__global__ __launch_bounds__(256)
void gather_cinp(const float* __restrict__ corr, const int* __restrict__ w,
                 float* __restrict__ cinp)
{
  const int b = blockIdx.x, tid = threadIdx.x;
  const int wi = w[b];
  const float* base = corr + (size_t)b * T_ * D_;
  const int nv = 3 - (wi == 0 ? 1 : 0) - (wi == T_ - 1 ? 1 : 0);
  const float inv = 1.f / (float)nv;
  const int d = tid << 2;
  const float4 cur = *(const float4*)(base + (size_t)wi * D_ + d);
  float4 acc = cur;
  if (wi > 0) {
    const float4 p = *(const float4*)(base + (size_t)(wi - 1) * D_ + d);
    acc.x += p.x; acc.y += p.y; acc.z += p.z; acc.w += p.w;
  }
  if (wi < T_ - 1) {
    const float4 p = *(const float4*)(base + (size_t)(wi + 1) * D_ + d);
    acc.x += p.x; acc.y += p.y; acc.z += p.z; acc.w += p.w;
  }
  acc.x *= inv; acc.y *= inv; acc.z *= inv; acc.w *= inv;
  *(float4*)(cinp + (size_t)b * (2 * D_) + d) = cur;
  *(float4*)(cinp + (size_t)b * (2 * D_) + D_ + d) = acc;
}

__global__ __launch_bounds__(256)
void apply_corr(float* __restrict__ corr, const int* __restrict__ w,
                const int* __restrict__ hasbad, const float* __restrict__ ns)
{
  const int b = blockIdx.x;
  if (!hasbad[b]) return;
  const int wi = w[b], tid = threadIdx.x;
  *(float4*)(corr + (size_t)(b * T_ + wi) * D_ + (tid << 2)) =
      *(const float4*)(ns + (size_t)b * D_ + (tid << 2));
}

__global__ __launch_bounds__(256)
void init_copy(const float* __restrict__ chain, float* __restrict__ corr,
               int* __restrict__ counts)
{
  const size_t i = ((size_t)blockIdx.x * 256 + threadIdx.x) << 2;
  *(float4*)(corr + i) = *(const float4*)(chain + i);
  if (blockIdx.x == 0 && threadIdx.x < B_) counts[threadIdx.x] = 0;
}

__global__ __launch_bounds__(256)
void finalize_k(const float* __restrict__ s0, const float* __restrict__ fs,
                const int* __restrict__ cnt, float* __restrict__ oc,
                float* __restrict__ oi)
{
  const int b = blockIdx.x, tid = threadIdx.x;
  const int wave = tid >> 6, lane = tid & 63;
  float a = s0[b * T_ + tid] + s0[b * T_ + tid + 256];
  float c = fs[b * T_ + tid] + fs[b * T_ + tid + 256];
  for (int off = 32; off; off >>= 1) {
    a += __shfl_down(a, off, 64);
    c += __shfl_down(c, off, 64);
  }
  __shared__ float ra[4], rc[4];
  if (!lane) { ra[wave] = a; rc[wave] = c; }
  __syncthreads();
  if (!tid) {
    const float as = ra[0] + ra[1] + ra[2] + ra[3];
    const float cs = rc[0] + rc[1] + rc[2] + rc[3];
    oc[b] = (float)cnt[b];
    oi[b] = (cs > as) ? 1.f : 0.f;
  }
}

// ---------------------------------------------------------------------------
extern "C" void kernel_launch(void* const* d_in, const int* in_sizes, int n_in,
                              void* d_out, int out_size, void* d_ws, size_t ws_size,
                              hipStream_t stream)
{
  const float* chain  = (const float*)d_in[0];
  const float* Wqkv   = (const float*)d_in[1];
  const float* bqkv   = (const float*)d_in[2];
  const float* Wo     = (const float*)d_in[3];
  const float* bo     = (const float*)d_in[4];
  const float* ln1g   = (const float*)d_in[5];
  const float* ln1b   = (const float*)d_in[6];
  const float* W1     = (const float*)d_in[7];
  const float* b1     = (const float*)d_in[8];
  const float* W2     = (const float*)d_in[9];
  const float* b2     = (const float*)d_in[10];
  const float* ln2g   = (const float*)d_in[11];
  const float* ln2b   = (const float*)d_in[12];
  const float* rhW1   = (const float*)d_in[13];
  const float* rhb1   = (const float*)d_in[14];
  const float* rhW2   = (const float*)d_in[15];
  const float* rhb2   = (const float*)d_in[16];
  const float* corW1  = (const float*)d_in[17];
  const float* corb1  = (const float*)d_in[18];
  const float* corW2  = (const float*)d_in[19];
  const float* corb2  = (const float*)d_in[20];

  float* ws = (float*)d_ws;
  // RegionB [0 .. 12,582,912): QKV16 bf16 (Q,K) / PRE f32 / E f32
  ushort_t* QKV16 = (ushort_t*)ws;
  float*    PRE   = ws;
  float*    E     = ws;
  // RegionH [12,582,912 .. 29,360,128): Hb bf16 FF hidden (FF1->FF2)
  //   ALIASED with Vtg bf16 (QKV-gemm -> flash) — live ranges disjoint.
  ushort_t* Hb    = (ushort_t*)(ws + 12582912);
  ushort_t* Vtg   = (ushort_t*)(ws + 12582912);   // 8,388,608 ushorts
  // Xb bf16 activations [29,360,128 .. 33,554,432)
  ushort_t* Xb    = (ushort_t*)(ws + 29360128);
  // AOb bf16 / HH f32 / run_iter scratch [33,554,432 .. 37,748,736)
  ushort_t* AOb   = (ushort_t*)(ws + 33554432);
  float*    HH    = ws + 33554432;
  float*    cinp  = ws + 33554432;
  float*    corrH = cinp + 32768;
  float*    nstep = corrH + 32768;
  // bf16 weights blob [37,748,736 .. 50,593,792)
  ushort_t* W16     = (ushort_t*)(ws + 37748736);
  ushort_t* Wqkv16  = W16;
  ushort_t* Wo16    = W16 + 6291456;
  ushort_t* W116    = W16 + 8388608;
  ushort_t* W216    = W16 + 16777216;
  ushort_t* rhW116  = W16 + 25165824;
  // small persistent buffers
  float* s0buf = ws + 50593792;
  float* sbuf  = s0buf + 8192;
  int* wbuf   = (int*)(sbuf + 8192);
  int* badbuf = wbuf + 16;
  int* cntbuf = badbuf + 16;

  float* outCorr   = (float*)d_out;
  float* outCounts = outCorr + 8388608;
  float* outFS     = outCounts + 16;
  float* outImpr   = outFS + 8192;

  const dim3 blk2(16, 16);
  const dim3 blk1(256);

  cvt_f32_bf16<<<dim3(6144), blk1, 0, stream>>>(Wqkv, Wqkv16, 6291456);
  cvt_f32_bf16<<<dim3(2048), blk1, 0, stream>>>(Wo,   Wo16,   2097152);
  cvt_f32_bf16<<<dim3(8192), blk1, 0, stream>>>(W1,   W116,   8388608);
  cvt_f32_bf16<<<dim3(8192), blk1, 0, stream>>>(W2,   W216,   8388608);
  cvt_f32_bf16<<<dim3(512),  blk1, 0, stream>>>(rhW1, rhW116, 524288);

  auto run_prm = [&](const float* xin, float* scoresOut) {
    cvt_f32_bf16<<<dim3(8192), blk1, 0, stream>>>(xin, Xb, 8388608);
    for (int l = 0; l < 2; ++l) {
      gemm_bf16<<<dim3(24, 64), blk1, 0, stream>>>(
          Xb, Wqkv16 + (size_t)l * 3 * D_ * D_, bqkv + (size_t)l * 3 * D_,
          nullptr, nullptr, QKV16, Vtg, M_, 3 * D_, D_,
          GF_OUTBF16 | GF_SPLITV);
      flash_attn<<<dim3(8, 64), blk1, 0, stream>>>(QKV16, Vtg, AOb);
      gemm_bf16<<<dim3(8, 64), blk1, 0, stream>>>(
          AOb, Wo16 + (size_t)l * D_ * D_, bo + (size_t)l * D_,
          Xb, PRE, nullptr, nullptr, M_, D_, D_, GF_RES);
      layernorm_k<<<dim3(M_), blk1, 0, stream>>>(PRE, ln1g + l * D_,
                                                 ln1b + l * D_, Xb);
      gemm_bf16<<<dim3(32, 64), blk1, 0, stream>>>(
          Xb, W116 + (size_t)l * FF_ * D_, b1 + (size_t)l * FF_,
          nullptr, nullptr, Hb, nullptr, M_, FF_, D_, GF_RELU | GF_OUTBF16);
      gemm_bf16<<<dim3(8, 64), blk1, 0, stream>>>(
          Hb, W216 + (size_t)l * D_ * FF_, b2 + (size_t)l * D_,
          Xb, E, nullptr, nullptr, M_, D_, FF_, GF_RES);
      layernorm_k<<<dim3(M_), blk1, 0, stream>>>(E, ln2g + l * D_,
                                                 ln2b + l * D_, Xb);
    }
    gemm_bf16<<<dim3(4, 64), blk1, 0, stream>>>(
        Xb, rhW116, rhb1, nullptr, HH, nullptr, nullptr, M_, 512, D_, GF_RELU);
    head2_sigmoid<<<dim3(M_ / 4), blk1, 0, stream>>>(HH, rhW2, rhb2, scoresOut);
  };

  auto run_iter = [&](const float* sPtr) {
    select_worst<<<dim3(B_), blk1, 0, stream>>>(sPtr, wbuf, badbuf, cntbuf);
    gather_cinp<<<dim3(B_), blk1, 0, stream>>>(outCorr, wbuf, cinp);
    gemm_bt<<<dim3(32, 1), blk2, 0, stream>>>(cinp, corW1, corb1, corrH,
                                              B_, 2 * D_, 2 * D_, GF_RELU);
    gemm_bt<<<dim3(16, 1), blk2, 0, stream>>>(corrH, corW2, corb2, nstep,
                                              B_, D_, 2 * D_, 0);
    apply_corr<<<dim3(B_), blk1, 0, stream>>>(outCorr, wbuf, badbuf, nstep);
  };

  init_copy<<<dim3(8192), blk1, 0, stream>>>(chain, outCorr, cntbuf);

  run_prm(chain, s0buf);
  run_iter(s0buf);
  run_prm(outCorr, sbuf);
  run_iter(sbuf);
  run_prm(outCorr, sbuf);
  run_iter(sbuf);
  run_prm(outCorr, outFS);
  finalize_k<<<dim3(B_), blk1, 0, stream>>>(s0buf, outFS, cntbuf,
                                            outCounts, outImpr);
  (void)in_sizes; (void)n_in; (void)out_size; (void)ws_size;
}

// Round 6
// 5135.845 us; speedup vs baseline: 5.8481x; 1.0196x over previous
//
#include <hip/hip_runtime.h>
#include <math.h>

#define B_ 16
#define T_ 512
#define D_ 1024
#define H_ 4
#define DH_ 256
#define FF_ 4096
#define M_ (B_*T_)
#define THRESH_ 0.3f
#define EPS_ 1e-5f

#define GF_RELU 1
#define GF_RES  2
#define GF_OUTBF16 4
#define GF_SPLITV 8

typedef unsigned short ushort_t;
typedef unsigned int uint_t;

using s16x8 = __attribute__((ext_vector_type(8))) short;
using f32x4 = __attribute__((ext_vector_type(4))) float;
using f32x16 = __attribute__((ext_vector_type(16))) float;

typedef const __attribute__((address_space(1))) void* gas_ptr;
typedef __attribute__((address_space(3))) void* lds_ptr;

static __device__ __forceinline__ ushort_t f2bf(float f) {
  uint_t x = __float_as_uint(f);
  return (ushort_t)((x + 0x7FFFu + ((x >> 16) & 1u)) >> 16);  // RNE
}
static __device__ __forceinline__ float bf2f(ushort_t u) {
  return __uint_as_float(((uint_t)u) << 16);
}

// ---------------------------------------------------------------------------
__global__ __launch_bounds__(256)
void cvt_f32_bf16(const float* __restrict__ in, ushort_t* __restrict__ out, int n)
{
  const int i = (blockIdx.x * 256 + threadIdx.x) << 2;
  if (i >= n) return;
  const float4 v = *(const float4*)(in + i);
  ushort4 o;
  o.x = f2bf(v.x); o.y = f2bf(v.y); o.z = f2bf(v.z); o.w = f2bf(v.w);
  *(ushort4*)(out + i) = o;
}

// ---------------------------------------------------------------------------
// bf16 MFMA GEMM: out[M,N] = A[M,K]*Bt[N,K]^T + bias (+res)(relu).
// 128x128 tile, BK=32, 4 waves, each wave 2x2 of 32x32x16 MFMAs.
// Group-M swizzle (GROUP=8) for L2 weight-tile reuse. gridDim.y % 8 == 0.
// GF_SPLITV: cols >= 2048 (V of QKV) -> vt[bh][t>>5][d][t&31].
// ---------------------------------------------------------------------------
__global__ __launch_bounds__(256)
void gemm_bf16(const ushort_t* __restrict__ A, const ushort_t* __restrict__ Bt,
               const float* __restrict__ bias, const ushort_t* __restrict__ res,
               float* __restrict__ outF, ushort_t* __restrict__ outB,
               ushort_t* __restrict__ vt,
               int M, int N, int K, int flags)
{
  __shared__ ushort_t As[128 * 32];
  __shared__ ushort_t Bs[128 * 32];
  // ---- group-M swizzled tile coordinates ----
  const int npn = gridDim.x;
  const int pid = blockIdx.y * npn + blockIdx.x;
  const int group = 8 * npn;
  const int first_m = (pid / group) * 8;
  const int pid_m = first_m + (pid % 8);
  const int pid_n = (pid % group) >> 3;
  const int n0 = pid_n << 7;
  const int m0 = pid_m << 7;

  const int tid = threadIdx.x;
  const int wv = tid >> 6, ln = tid & 63;
  const int wm = (wv >> 1) << 6;     // wave m-offset: 0/64
  const int wn = (wv & 1) << 6;      // wave n-offset: 0/64
  const int col32 = ln & 31, l5 = ln >> 5;

  f32x16 acc[2][2] = {};

  const ushort_t* ga = A + (size_t)(m0 + wv * 16 + (ln >> 2)) * K + ((ln & 3) << 3);
  const ushort_t* gb = Bt + (size_t)(n0 + wv * 16 + (ln >> 2)) * K + ((ln & 3) << 3);
  ushort_t* lA = &As[wv * 512];
  ushort_t* lB = &Bs[wv * 512];

  for (int k0 = 0; k0 < K; k0 += 32) {
    __builtin_amdgcn_global_load_lds((gas_ptr)(const void*)ga,
                                     (lds_ptr)(void*)lA, 16, 0, 0);
    __builtin_amdgcn_global_load_lds((gas_ptr)(const void*)(ga + (size_t)64 * K),
                                     (lds_ptr)(void*)(lA + 2048), 16, 0, 0);
    __builtin_amdgcn_global_load_lds((gas_ptr)(const void*)gb,
                                     (lds_ptr)(void*)lB, 16, 0, 0);
    __builtin_amdgcn_global_load_lds((gas_ptr)(const void*)(gb + (size_t)64 * K),
                                     (lds_ptr)(void*)(lB + 2048), 16, 0, 0);
    ga += 32; gb += 32;
    __syncthreads();
    // A-frag (32x32x16): lane holds A[row=col32][k=l5*8+j]; k-half kh adds 16
    s16x8 af[2][2], bfr[2][2];
#pragma unroll
    for (int mt = 0; mt < 2; ++mt)
#pragma unroll
      for (int kh = 0; kh < 2; ++kh)
        af[mt][kh] = *(const s16x8*)(&As[(wm + mt * 32 + col32) * 32
                                         + kh * 16 + l5 * 8]);
#pragma unroll
    for (int nt = 0; nt < 2; ++nt)
#pragma unroll
      for (int kh = 0; kh < 2; ++kh)
        bfr[nt][kh] = *(const s16x8*)(&Bs[(wn + nt * 32 + col32) * 32
                                          + kh * 16 + l5 * 8]);
#pragma unroll
    for (int kh = 0; kh < 2; ++kh)
#pragma unroll
      for (int mt = 0; mt < 2; ++mt)
#pragma unroll
        for (int nt = 0; nt < 2; ++nt)
          acc[mt][nt] = __builtin_amdgcn_mfma_f32_32x32x16_bf16(
              af[mt][kh], bfr[nt][kh], acc[mt][nt], 0, 0, 0);
    __syncthreads();
  }

  // Epilogue. C/D 32x32 layout: col=lane&31, row=(reg&3)+8*(reg>>2)+4*(lane>>5)
#pragma unroll
  for (int mt = 0; mt < 2; ++mt)
#pragma unroll
    for (int nt = 0; nt < 2; ++nt) {
      const int c = n0 + wn + nt * 32 + col32;
      const float bb = bias[c];
      const bool isV = (flags & GF_SPLITV) && (c >= 2048);
#pragma unroll
      for (int reg = 0; reg < 16; ++reg) {
        const int row = m0 + wm + mt * 32 + (reg & 3) + ((reg >> 2) << 3)
                        + (l5 << 2);
        float v = acc[mt][nt][reg] + bb;
        const size_t idx = (size_t)row * N + c;
        if (flags & GF_RES) v += bf2f(res[idx]);
        if (flags & GF_RELU) v = fmaxf(v, 0.f);
        if (isV) {
          const int t = row & 511, bb2 = row >> 9;
          const int hh = (c - 2048) >> 8, d = (c - 2048) & 255;
          vt[(((size_t)(bb2 * 4 + hh) * 16 + (t >> 5)) << 13) + d * 32 + (t & 31)]
              = f2bf(v);
        } else if (flags & GF_OUTBF16) outB[idx] = f2bf(v);
        else outF[idx] = v;
      }
    }
}

// ---------------------------------------------------------------------------
// Fused flash attention. Q frags in registers, K/V double-buffered in LDS via
// global_load_lds, online softmax, MFMA QK^T & PV. P carried as hi+lo bf16.
// ---------------------------------------------------------------------------
__global__ __launch_bounds__(256)
void flash_attn(const ushort_t* __restrict__ qkv, const ushort_t* __restrict__ vtg,
                ushort_t* __restrict__ ao)
{
  __shared__ ushort_t Ks[2][8 * 64 * 32];     // [buf][kc*64+row][32]
  __shared__ ushort_t Vs[2][2 * 256 * 32];    // [buf][c*256+d][32]
  __shared__ ushort_t Ph[4][16][80];          // wave-private P hi
  __shared__ ushort_t Pl[4][16][80];          // wave-private P lo
  const int qt = (int)gridDim.x - 1 - blockIdx.x;   // heavy-first
  const int t0 = qt << 6;
  const int bh = blockIdx.y;
  const int b = bh >> 2, h = bh & 3;
  const int nIter = qt + 1;
  const int tid = threadIdx.x;
  const int wv = tid >> 6, ln = tid & 63;
  const int lrow = ln & 15, quad = ln >> 4;

  s16x8 qf[8];
  {
    const ushort_t* qrow = qkv + (size_t)(b * T_ + t0 + wv * 16 + lrow) * 3072
                           + h * 256 + quad * 8;
#pragma unroll
    for (int kc = 0; kc < 8; ++kc)
      qf[kc] = *(const s16x8*)(qrow + kc * 32);
  }

  const ushort_t* kg = qkv + (size_t)(b * T_) * 3072 + 1024 + h * 256;
  const ushort_t* vg = vtg + (size_t)bh * 131072;

  auto issue_k = [&](int i, int buf) {
#pragma unroll
    for (int iss = 0; iss < 8; ++iss) {
      const int R = 128 * wv + 16 * iss + (ln >> 2);
      const ushort_t* g = kg + (size_t)(64 * i + (R & 63)) * 3072
                          + (R >> 6) * 32 + ((ln & 3) << 3);
      ushort_t* l = &Ks[buf][(128 * wv + 16 * iss) * 32];
      __builtin_amdgcn_global_load_lds((gas_ptr)(const void*)g,
                                       (lds_ptr)(void*)l, 16, 0, 0);
    }
  };
  auto issue_v = [&](int i, int buf) {
#pragma unroll
    for (int iss = 0; iss < 8; ++iss) {   // 8 x 512 = full 4096/wave
      const ushort_t* g = vg + (size_t)i * 16384 + wv * 4096 + iss * 512 + ln * 8;
      ushort_t* l = &Vs[buf][wv * 4096 + iss * 512];
      __builtin_amdgcn_global_load_lds((gas_ptr)(const void*)g,
                                       (lds_ptr)(void*)l, 16, 0, 0);
    }
  };

  issue_k(0, 0);
  issue_v(0, 0);

  f32x4 o[16] = {};
  float Mx[4], L[4];
#pragma unroll
  for (int r = 0; r < 4; ++r) { Mx[r] = -3.0e38f; L[r] = 0.f; }

  for (int it = 0; it < nIter; ++it) {
    const int buf = it & 1;
    __syncthreads();   // vmcnt(0)+barrier: tile `it` fully resident
    if (it + 1 < nIter) { issue_k(it + 1, buf ^ 1); issue_v(it + 1, buf ^ 1); }

    // S = Q.K^T
    f32x4 s[4] = {};
#pragma unroll
    for (int kc = 0; kc < 8; ++kc)
#pragma unroll
      for (int j = 0; j < 4; ++j) {
        const s16x8 bfv = *(const s16x8*)(&Ks[buf][(kc * 64 + 16 * j + lrow) * 32
                                                   + quad * 8]);
        s[j] = __builtin_amdgcn_mfma_f32_16x16x32_bf16(qf[kc], bfv, s[j], 0, 0, 0);
      }

    const bool diag = (it == qt);
#pragma unroll
    for (int j = 0; j < 4; ++j)
#pragma unroll
      for (int r = 0; r < 4; ++r) {
        float v = s[j][r] * 0.0625f;
        if (diag && (16 * j + lrow > 16 * wv + quad * 4 + r)) v = -INFINITY;
        s[j][r] = v;
      }

    // online softmax (row = quad*4+r, spread over the quad's 16 lanes)
    float alpha[4];
#pragma unroll
    for (int r = 0; r < 4; ++r) {
      float m = fmaxf(fmaxf(s[0][r], s[1][r]), fmaxf(s[2][r], s[3][r]));
      m = fmaxf(m, __shfl_xor(m, 1));
      m = fmaxf(m, __shfl_xor(m, 2));
      m = fmaxf(m, __shfl_xor(m, 4));
      m = fmaxf(m, __shfl_xor(m, 8));
      const float mn = fmaxf(Mx[r], m);
      alpha[r] = __expf(Mx[r] - mn);
      Mx[r] = mn;
      float l = 0.f;
#pragma unroll
      for (int j = 0; j < 4; ++j) {
        const float p = __expf(s[j][r] - mn);
        s[j][r] = p;
        l += p;
      }
      l += __shfl_xor(l, 1);
      l += __shfl_xor(l, 2);
      l += __shfl_xor(l, 4);
      l += __shfl_xor(l, 8);
      L[r] = L[r] * alpha[r] + l;
    }

    // P -> LDS as hi+lo bf16 pair (C-layout -> A-layout); rescale O
#pragma unroll
    for (int j = 0; j < 4; ++j)
#pragma unroll
      for (int r = 0; r < 4; ++r) {
        const float p = s[j][r];
        const ushort_t hi = f2bf(p);
        Ph[wv][quad * 4 + r][16 * j + lrow] = hi;
        Pl[wv][quad * 4 + r][16 * j + lrow] = f2bf(p - bf2f(hi));
      }
#pragma unroll
    for (int jd = 0; jd < 16; ++jd)
#pragma unroll
      for (int r = 0; r < 4; ++r)
        o[jd][r] *= alpha[r];

    // O += (P_hi + P_lo).V
#pragma unroll
    for (int c = 0; c < 2; ++c) {
      const s16x8 ph = *(const s16x8*)(&Ph[wv][lrow][32 * c + quad * 8]);
      const s16x8 pl = *(const s16x8*)(&Pl[wv][lrow][32 * c + quad * 8]);
#pragma unroll
      for (int jd = 0; jd < 16; ++jd) {
        const s16x8 vb = *(const s16x8*)(&Vs[buf][(c * 256 + 16 * jd + lrow) * 32
                                                  + quad * 8]);
        o[jd] = __builtin_amdgcn_mfma_f32_16x16x32_bf16(ph, vb, o[jd], 0, 0, 0);
        o[jd] = __builtin_amdgcn_mfma_f32_16x16x32_bf16(pl, vb, o[jd], 0, 0, 0);
      }
    }
  }

  float inv[4];
#pragma unroll
  for (int r = 0; r < 4; ++r) inv[r] = 1.f / L[r];
  ushort_t* aob = ao + (size_t)(b * T_ + t0 + 16 * wv + quad * 4) * 1024 + h * 256;
#pragma unroll
  for (int jd = 0; jd < 16; ++jd)
#pragma unroll
    for (int r = 0; r < 4; ++r)
      aob[(size_t)r * 1024 + 16 * jd + lrow] = f2bf(o[jd][r] * inv[r]);
}

// ---------------------------------------------------------------------------
// fp32 tiled GEMM (tiny correction MLP only, M=16).
// ---------------------------------------------------------------------------
__global__ __launch_bounds__(256)
void gemm_bt(const float* __restrict__ A, const float* __restrict__ Bt,
             const float* __restrict__ bias, float* __restrict__ out,
             int M, int N, int K, int flags)
{
  __shared__ float As[16][68];
  __shared__ float Bs[16][68];
  const int n0 = blockIdx.x << 6;
  const int m0 = blockIdx.y << 6;
  const int tx = threadIdx.x, ty = threadIdx.y;
  const int tid = (ty << 4) + tx;
  const int lr = tid >> 2;
  const int lc = (tid & 3) << 2;
  float c[4][4] = {};
  for (int k0 = 0; k0 < K; k0 += 16) {
    float4 av = make_float4(0.f, 0.f, 0.f, 0.f);
    if (m0 + lr < M)
      av = *(const float4*)(A + (size_t)(m0 + lr) * K + k0 + lc);
    const float4 bv = *(const float4*)(Bt + (size_t)(n0 + lr) * K + k0 + lc);
    As[lc + 0][lr] = av.x; As[lc + 1][lr] = av.y;
    As[lc + 2][lr] = av.z; As[lc + 3][lr] = av.w;
    Bs[lc + 0][lr] = bv.x; Bs[lc + 1][lr] = bv.y;
    Bs[lc + 2][lr] = bv.z; Bs[lc + 3][lr] = bv.w;
    __syncthreads();
#pragma unroll
    for (int k = 0; k < 16; ++k) {
      const float4 a = *(const float4*)(&As[k][ty << 2]);
      const float4 b = *(const float4*)(&Bs[k][tx << 2]);
      c[0][0] += a.x*b.x; c[0][1] += a.x*b.y; c[0][2] += a.x*b.z; c[0][3] += a.x*b.w;
      c[1][0] += a.y*b.x; c[1][1] += a.y*b.y; c[1][2] += a.y*b.z; c[1][3] += a.y*b.w;
      c[2][0] += a.z*b.x; c[2][1] += a.z*b.y; c[2][2] += a.z*b.z; c[2][3] += a.z*b.w;
      c[3][0] += a.w*b.x; c[3][1] += a.w*b.y; c[3][2] += a.w*b.z; c[3][3] += a.w*b.w;
    }
    __syncthreads();
  }
  const int n = n0 + (tx << 2);
  const float4 bb = *(const float4*)(bias + n);
#pragma unroll
  for (int i = 0; i < 4; ++i) {
    const int m = m0 + (ty << 2) + i;
    if (m >= M) break;
    float4 v = make_float4(c[i][0] + bb.x, c[i][1] + bb.y,
                           c[i][2] + bb.z, c[i][3] + bb.w);
    if (flags & GF_RELU) {
      v.x = fmaxf(v.x, 0.f); v.y = fmaxf(v.y, 0.f);
      v.z = fmaxf(v.z, 0.f); v.w = fmaxf(v.w, 0.f);
    }
    *(float4*)(out + (size_t)m * N + n) = v;
  }
}

// ---------------------------------------------------------------------------
__global__ __launch_bounds__(256)
void layernorm_k(const float* __restrict__ in, const float* __restrict__ g,
                 const float* __restrict__ bta, ushort_t* __restrict__ outb)
{
  const int row = blockIdx.x;
  const int tid = threadIdx.x;
  const int wave = tid >> 6, lane = tid & 63;
  const float4 v = *(const float4*)(in + (size_t)row * D_ + (tid << 2));
  float s = v.x + v.y + v.z + v.w;
  float ss = v.x*v.x + v.y*v.y + v.z*v.z + v.w*v.w;
  for (int off = 32; off; off >>= 1) {
    s  += __shfl_down(s, off, 64);
    ss += __shfl_down(ss, off, 64);
  }
  __shared__ float ra[4], rb[4];
  if (!lane) { ra[wave] = s; rb[wave] = ss; }
  __syncthreads();
  s  = ra[0] + ra[1] + ra[2] + ra[3];
  ss = rb[0] + rb[1] + rb[2] + rb[3];
  const float mu = s * (1.f / (float)D_);
  const float var = ss * (1.f / (float)D_) - mu * mu;
  const float rstd = rsqrtf(var + EPS_);
  const float4 gv = *(const float4*)(g + (tid << 2));
  const float4 bv = *(const float4*)(bta + (tid << 2));
  ushort4 o;
  o.x = f2bf((v.x - mu) * rstd * gv.x + bv.x);
  o.y = f2bf((v.y - mu) * rstd * gv.y + bv.y);
  o.z = f2bf((v.z - mu) * rstd * gv.z + bv.z);
  o.w = f2bf((v.w - mu) * rstd * gv.w + bv.w);
  *(ushort4*)(outb + (size_t)row * D_ + (tid << 2)) = o;
}

__global__ __launch_bounds__(256)
void head2_sigmoid(const float* __restrict__ h1, const float* __restrict__ w2,
                   const float* __restrict__ b2, float* __restrict__ sout)
{
  const int tid = threadIdx.x;
  const int wave = tid >> 6, lane = tid & 63;
  const int m = (blockIdx.x << 2) + wave;
  const float* hr = h1 + (size_t)m * 512;
  float s = 0.f;
#pragma unroll
  for (int i = 0; i < 8; ++i) s += hr[i * 64 + lane] * w2[i * 64 + lane];
  for (int off = 32; off; off >>= 1) s += __shfl_down(s, off, 64);
  if (!lane) sout[m] = 1.f / (1.f + expf(-(s + b2[0])));
}

__global__ __launch_bounds__(256)
void select_worst(const float* __restrict__ s, int* __restrict__ w,
                  int* __restrict__ hasbad, int* __restrict__ counts)
{
  const int b = blockIdx.x, tid = threadIdx.x;
  const float* sr = s + b * T_;
  float bv = INFINITY; int bi = 0;
  for (int i = tid; i < T_; i += 256) {
    const float v = sr[i];
    const float cand = (v < THRESH_) ? v : INFINITY;
    if (cand < bv || (cand == bv && i < bi)) { bv = cand; bi = i; }
  }
  __shared__ float rv[256];
  __shared__ int ri[256];
  rv[tid] = bv; ri[tid] = bi;
  __syncthreads();
  for (int str = 128; str; str >>= 1) {
    if (tid < str) {
      const float v2 = rv[tid + str]; const int i2 = ri[tid + str];
      if (v2 < rv[tid] || (v2 == rv[tid] && i2 < ri[tid])) { rv[tid] = v2; ri[tid] = i2; }
    }
    __syncthreads();
  }
  if (!tid) {
    const int bad = (rv[0] < INFINITY) ? 1 : 0;
    w[b] = ri[0];
    hasbad[b] = bad;
    counts[b] += bad;
  }
}

__global__ __launch_bounds__(256)
void gather_cinp(const float* __restrict__ corr, const int* __restrict__ w,
                 float* __restrict__ cinp)
{
  const int b = blockIdx.x, tid = threadIdx.x;
  const int wi = w[b];
  const float* base = corr + (size_t)b * T_ * D_;
  const int nv = 3 - (wi == 0 ? 1 : 0) - (wi == T_ - 1 ? 1 : 0);
  const float inv = 1.f / (float)nv;
  const int d = tid << 2;
  const float4 cur = *(const float4*)(base + (size_t)wi * D_ + d);
  float4 acc = cur;
  if (wi > 0) {
    const float4 p = *(const float4*)(base + (size_t)(wi - 1) * D_ + d);
    acc.x += p.x; acc.y += p.y; acc.z += p.z; acc.w += p.w;
  }
  if (wi < T_ - 1) {
    const float4 p = *(const float4*)(base + (size_t)(wi + 1) * D_ + d);
    acc.x += p.x; acc.y += p.y; acc.z += p.z; acc.w += p.w;
  }
  acc.x *= inv; acc.y *= inv; acc.z *= inv; acc.w *= inv;
  *(float4*)(cinp + (size_t)b * (2 * D_) + d) = cur;
  *(float4*)(cinp + (size_t)b * (2 * D_) + D_ + d) = acc;
}

__global__ __launch_bounds__(256)
void apply_corr(float* __restrict__ corr, const int* __restrict__ w,
                const int* __restrict__ hasbad, const float* __restrict__ ns)
{
  const int b = blockIdx.x;
  if (!hasbad[b]) return;
  const int wi = w[b], tid = threadIdx.x;
  *(float4*)(corr + (size_t)(b * T_ + wi) * D_ + (tid << 2)) =
      *(const float4*)(ns + (size_t)b * D_ + (tid << 2));
}

__global__ __launch_bounds__(256)
void init_copy(const float* __restrict__ chain, float* __restrict__ corr,
               int* __restrict__ counts)
{
  const size_t i = ((size_t)blockIdx.x * 256 + threadIdx.x) << 2;
  *(float4*)(corr + i) = *(const float4*)(chain + i);
  if (blockIdx.x == 0 && threadIdx.x < B_) counts[threadIdx.x] = 0;
}

__global__ __launch_bounds__(256)
void finalize_k(const float* __restrict__ s0, const float* __restrict__ fs,
                const int* __restrict__ cnt, float* __restrict__ oc,
                float* __restrict__ oi)
{
  const int b = blockIdx.x, tid = threadIdx.x;
  const int wave = tid >> 6, lane = tid & 63;
  float a = s0[b * T_ + tid] + s0[b * T_ + tid + 256];
  float c = fs[b * T_ + tid] + fs[b * T_ + tid + 256];
  for (int off = 32; off; off >>= 1) {
    a += __shfl_down(a, off, 64);
    c += __shfl_down(c, off, 64);
  }
  __shared__ float ra[4], rc[4];
  if (!lane) { ra[wave] = a; rc[wave] = c; }
  __syncthreads();
  if (!tid) {
    const float as = ra[0] + ra[1] + ra[2] + ra[3];
    const float cs = rc[0] + rc[1] + rc[2] + rc[3];
    oc[b] = (float)cnt[b];
    oi[b] = (cs > as) ? 1.f : 0.f;
  }
}

// ---------------------------------------------------------------------------
extern "C" void kernel_launch(void* const* d_in, const int* in_sizes, int n_in,
                              void* d_out, int out_size, void* d_ws, size_t ws_size,
                              hipStream_t stream)
{
  const float* chain  = (const float*)d_in[0];
  const float* Wqkv   = (const float*)d_in[1];
  const float* bqkv   = (const float*)d_in[2];
  const float* Wo     = (const float*)d_in[3];
  const float* bo     = (const float*)d_in[4];
  const float* ln1g   = (const float*)d_in[5];
  const float* ln1b   = (const float*)d_in[6];
  const float* W1     = (const float*)d_in[7];
  const float* b1     = (const float*)d_in[8];
  const float* W2     = (const float*)d_in[9];
  const float* b2     = (const float*)d_in[10];
  const float* ln2g   = (const float*)d_in[11];
  const float* ln2b   = (const float*)d_in[12];
  const float* rhW1   = (const float*)d_in[13];
  const float* rhb1   = (const float*)d_in[14];
  const float* rhW2   = (const float*)d_in[15];
  const float* rhb2   = (const float*)d_in[16];
  const float* corW1  = (const float*)d_in[17];
  const float* corb1  = (const float*)d_in[18];
  const float* corW2  = (const float*)d_in[19];
  const float* corb2  = (const float*)d_in[20];

  float* ws = (float*)d_ws;
  // RegionB [0 .. 12,582,912): QKV16 bf16 (Q,K) / PRE f32 / E f32
  ushort_t* QKV16 = (ushort_t*)ws;
  float*    PRE   = ws;
  float*    E     = ws;
  // RegionH [12,582,912 .. 29,360,128): Hb bf16 FF hidden (FF1->FF2)
  //   ALIASED with Vtg bf16 (QKV-gemm -> flash) — live ranges disjoint.
  ushort_t* Hb    = (ushort_t*)(ws + 12582912);
  ushort_t* Vtg   = (ushort_t*)(ws + 12582912);   // 8,388,608 ushorts
  // Xb bf16 activations [29,360,128 .. 33,554,432)
  ushort_t* Xb    = (ushort_t*)(ws + 29360128);
  // AOb bf16 / HH f32 / run_iter scratch [33,554,432 .. 37,748,736)
  ushort_t* AOb   = (ushort_t*)(ws + 33554432);
  float*    HH    = ws + 33554432;
  float*    cinp  = ws + 33554432;
  float*    corrH = cinp + 32768;
  float*    nstep = corrH + 32768;
  // bf16 weights blob [37,748,736 .. 50,593,792)
  ushort_t* W16     = (ushort_t*)(ws + 37748736);
  ushort_t* Wqkv16  = W16;
  ushort_t* Wo16    = W16 + 6291456;
  ushort_t* W116    = W16 + 8388608;
  ushort_t* W216    = W16 + 16777216;
  ushort_t* rhW116  = W16 + 25165824;
  // small persistent buffers
  float* s0buf = ws + 50593792;
  float* sbuf  = s0buf + 8192;
  int* wbuf   = (int*)(sbuf + 8192);
  int* badbuf = wbuf + 16;
  int* cntbuf = badbuf + 16;

  float* outCorr   = (float*)d_out;
  float* outCounts = outCorr + 8388608;
  float* outFS     = outCounts + 16;
  float* outImpr   = outFS + 8192;

  const dim3 blk2(16, 16);
  const dim3 blk1(256);

  cvt_f32_bf16<<<dim3(6144), blk1, 0, stream>>>(Wqkv, Wqkv16, 6291456);
  cvt_f32_bf16<<<dim3(2048), blk1, 0, stream>>>(Wo,   Wo16,   2097152);
  cvt_f32_bf16<<<dim3(8192), blk1, 0, stream>>>(W1,   W116,   8388608);
  cvt_f32_bf16<<<dim3(8192), blk1, 0, stream>>>(W2,   W216,   8388608);
  cvt_f32_bf16<<<dim3(512),  blk1, 0, stream>>>(rhW1, rhW116, 524288);

  auto run_prm = [&](const float* xin, float* scoresOut) {
    cvt_f32_bf16<<<dim3(8192), blk1, 0, stream>>>(xin, Xb, 8388608);
    for (int l = 0; l < 2; ++l) {
      gemm_bf16<<<dim3(24, 64), blk1, 0, stream>>>(
          Xb, Wqkv16 + (size_t)l * 3 * D_ * D_, bqkv + (size_t)l * 3 * D_,
          nullptr, nullptr, QKV16, Vtg, M_, 3 * D_, D_,
          GF_OUTBF16 | GF_SPLITV);
      flash_attn<<<dim3(8, 64), blk1, 0, stream>>>(QKV16, Vtg, AOb);
      gemm_bf16<<<dim3(8, 64), blk1, 0, stream>>>(
          AOb, Wo16 + (size_t)l * D_ * D_, bo + (size_t)l * D_,
          Xb, PRE, nullptr, nullptr, M_, D_, D_, GF_RES);
      layernorm_k<<<dim3(M_), blk1, 0, stream>>>(PRE, ln1g + l * D_,
                                                 ln1b + l * D_, Xb);
      gemm_bf16<<<dim3(32, 64), blk1, 0, stream>>>(
          Xb, W116 + (size_t)l * FF_ * D_, b1 + (size_t)l * FF_,
          nullptr, nullptr, Hb, nullptr, M_, FF_, D_, GF_RELU | GF_OUTBF16);
      gemm_bf16<<<dim3(8, 64), blk1, 0, stream>>>(
          Hb, W216 + (size_t)l * D_ * FF_, b2 + (size_t)l * D_,
          Xb, E, nullptr, nullptr, M_, D_, FF_, GF_RES);
      layernorm_k<<<dim3(M_), blk1, 0, stream>>>(E, ln2g + l * D_,
                                                 ln2b + l * D_, Xb);
    }
    gemm_bf16<<<dim3(4, 64), blk1, 0, stream>>>(
        Xb, rhW116, rhb1, nullptr, HH, nullptr, nullptr, M_, 512, D_, GF_RELU);
    head2_sigmoid<<<dim3(M_ / 4), blk1, 0, stream>>>(HH, rhW2, rhb2, scoresOut);
  };

  auto run_iter = [&](const float* sPtr) {
    select_worst<<<dim3(B_), blk1, 0, stream>>>(sPtr, wbuf, badbuf, cntbuf);
    gather_cinp<<<dim3(B_), blk1, 0, stream>>>(outCorr, wbuf, cinp);
    gemm_bt<<<dim3(32, 1), blk2, 0, stream>>>(cinp, corW1, corb1, corrH,
                                              B_, 2 * D_, 2 * D_, GF_RELU);
    gemm_bt<<<dim3(16, 1), blk2, 0, stream>>>(corrH, corW2, corb2, nstep,
                                              B_, D_, 2 * D_, 0);
    apply_corr<<<dim3(B_), blk1, 0, stream>>>(outCorr, wbuf, badbuf, nstep);
  };

  init_copy<<<dim3(8192), blk1, 0, stream>>>(chain, outCorr, cntbuf);

  run_prm(chain, s0buf);
  run_iter(s0buf);
  run_prm(outCorr, sbuf);
  run_iter(sbuf);
  run_prm(outCorr, sbuf);
  run_iter(sbuf);
  run_prm(outCorr, outFS);
  finalize_k<<<dim3(B_), blk1, 0, stream>>>(s0buf, outFS, cntbuf,
                                            outCounts, outImpr);
  (void)in_sizes; (void)n_in; (void)out_size; (void)ws_size;
}

// Round 7
// 4612.372 us; speedup vs baseline: 6.5118x; 1.1135x over previous
//
#include <hip/hip_runtime.h>
#include <math.h>

#define B_ 16
#define T_ 512
#define D_ 1024
#define H_ 4
#define DH_ 256
#define FF_ 4096
#define M_ (B_*T_)
#define THRESH_ 0.3f
#define EPS_ 1e-5f

#define GF_RELU 1
#define GF_RES  2
#define GF_OUTBF16 4
#define GF_SPLITV 8

typedef unsigned short ushort_t;
typedef unsigned int uint_t;

using s16x8 = __attribute__((ext_vector_type(8))) short;
using f32x4 = __attribute__((ext_vector_type(4))) float;
using f32x16 = __attribute__((ext_vector_type(16))) float;

typedef const __attribute__((address_space(1))) void* gas_ptr;
typedef __attribute__((address_space(3))) void* lds_ptr;

static __device__ __forceinline__ ushort_t f2bf(float f) {
  uint_t x = __float_as_uint(f);
  return (ushort_t)((x + 0x7FFFu + ((x >> 16) & 1u)) >> 16);  // RNE
}
static __device__ __forceinline__ float bf2f(ushort_t u) {
  return __uint_as_float(((uint_t)u) << 16);
}

// ---------------------------------------------------------------------------
__global__ __launch_bounds__(256)
void cvt_f32_bf16(const float* __restrict__ in, ushort_t* __restrict__ out, int n)
{
  const int i = (blockIdx.x * 256 + threadIdx.x) << 2;
  if (i >= n) return;
  const float4 v = *(const float4*)(in + i);
  ushort4 o;
  o.x = f2bf(v.x); o.y = f2bf(v.y); o.z = f2bf(v.z); o.w = f2bf(v.w);
  *(ushort4*)(out + i) = o;
}

// ---------------------------------------------------------------------------
// bf16 MFMA GEMM: out[M,N] = A[M,K]*Bt[N,K]^T + bias (+res)(relu).
// 128x128 tile, BK=64, XOR-swizzled LDS staging (chunk c of row r lives at
// position c^(r&7)) -> conflict-free ds_read_b128 for the 32x32x16 fragments.
// 4 waves, each 2x2 of 32x32x16 MFMAs. Group-M swizzle (GROUP=8).
// K % 64 == 0, N % 128 == 0, M % 128 == 0. gridDim.y % 8 == 0.
// GF_SPLITV: cols >= 2048 (V of QKV) -> vt[bh][t>>5][d][t&31].
// ---------------------------------------------------------------------------
__global__ __launch_bounds__(256)
void gemm_bf16(const ushort_t* __restrict__ A, const ushort_t* __restrict__ Bt,
               const float* __restrict__ bias, const ushort_t* __restrict__ res,
               float* __restrict__ outF, ushort_t* __restrict__ outB,
               ushort_t* __restrict__ vt,
               int M, int N, int K, int flags)
{
  __shared__ ushort_t As[128 * 64];
  __shared__ ushort_t Bs[128 * 64];
  // ---- group-M swizzled tile coordinates ----
  const int npn = gridDim.x;
  const int pid = blockIdx.y * npn + blockIdx.x;
  const int group = 8 * npn;
  const int first_m = (pid / group) * 8;
  const int pid_m = first_m + (pid % 8);
  const int pid_n = (pid % group) >> 3;
  const int n0 = pid_n << 7;
  const int m0 = pid_m << 7;

  const int tid = threadIdx.x;
  const int wv = tid >> 6, ln = tid & 63;
  const int wm = (wv >> 1) << 6;     // wave m-offset: 0/64
  const int wn = (wv & 1) << 6;      // wave n-offset: 0/64
  const int col32 = ln & 31, l5 = ln >> 5;

  f32x16 acc[2][2] = {};

  // staging: wave wv covers rows [wv*32, wv*32+32), 4 issues of 8 rows each.
  // lane ln -> row_off = ln>>3, pos = ln&7, src chunk = pos ^ (row&7).
  const int srow = (ln >> 3);
  const int schunk = (ln & 7) ^ srow;          // row&7 == srow (rows 8-aligned)
  const ushort_t* gaBase = A + (size_t)(m0 + wv * 32 + srow) * K + schunk * 8;
  const ushort_t* gbBase = Bt + (size_t)(n0 + wv * 32 + srow) * K + schunk * 8;
  ushort_t* lA = &As[wv * 2048];
  ushort_t* lB = &Bs[wv * 2048];

  for (int k0 = 0; k0 < K; k0 += 64) {
#pragma unroll
    for (int iss = 0; iss < 4; ++iss) {
      __builtin_amdgcn_global_load_lds(
          (gas_ptr)(const void*)(gaBase + (size_t)(iss * 8) * K + k0),
          (lds_ptr)(void*)(lA + iss * 512), 16, 0, 0);
      __builtin_amdgcn_global_load_lds(
          (gas_ptr)(const void*)(gbBase + (size_t)(iss * 8) * K + k0),
          (lds_ptr)(void*)(lB + iss * 512), 16, 0, 0);
    }
    __syncthreads();
#pragma unroll
    for (int kh = 0; kh < 4; ++kh) {
      s16x8 af[2], bfr[2];
#pragma unroll
      for (int mt = 0; mt < 2; ++mt) {
        const int row = wm + mt * 32 + col32;
        const int pos = ((kh << 1) + l5) ^ (col32 & 7);
        af[mt] = *(const s16x8*)(&As[row * 64 + pos * 8]);
      }
#pragma unroll
      for (int nt = 0; nt < 2; ++nt) {
        const int row = wn + nt * 32 + col32;
        const int pos = ((kh << 1) + l5) ^ (col32 & 7);
        bfr[nt] = *(const s16x8*)(&Bs[row * 64 + pos * 8]);
      }
#pragma unroll
      for (int mt = 0; mt < 2; ++mt)
#pragma unroll
        for (int nt = 0; nt < 2; ++nt)
          acc[mt][nt] = __builtin_amdgcn_mfma_f32_32x32x16_bf16(
              af[mt], bfr[nt], acc[mt][nt], 0, 0, 0);
    }
    __syncthreads();
  }

  // Epilogue. C/D 32x32 layout: col=lane&31, row=(reg&3)+8*(reg>>2)+4*(lane>>5)
#pragma unroll
  for (int mt = 0; mt < 2; ++mt)
#pragma unroll
    for (int nt = 0; nt < 2; ++nt) {
      const int c = n0 + wn + nt * 32 + col32;
      const float bb = bias[c];
      const bool isV = (flags & GF_SPLITV) && (c >= 2048);
#pragma unroll
      for (int reg = 0; reg < 16; ++reg) {
        const int row = m0 + wm + mt * 32 + (reg & 3) + ((reg >> 2) << 3)
                        + (l5 << 2);
        float v = acc[mt][nt][reg] + bb;
        const size_t idx = (size_t)row * N + c;
        if (flags & GF_RES) v += bf2f(res[idx]);
        if (flags & GF_RELU) v = fmaxf(v, 0.f);
        if (isV) {
          const int t = row & 511, bb2 = row >> 9;
          const int hh = (c - 2048) >> 8, d = (c - 2048) & 255;
          vt[(((size_t)(bb2 * 4 + hh) * 16 + (t >> 5)) << 13) + d * 32 + (t & 31)]
              = f2bf(v);
        } else if (flags & GF_OUTBF16) outB[idx] = f2bf(v);
        else outF[idx] = v;
      }
    }
}

// ---------------------------------------------------------------------------
// Fused flash attention. Q frags in registers, K/V double-buffered in LDS via
// global_load_lds, online softmax, MFMA QK^T & PV. P carried as hi+lo bf16.
// ---------------------------------------------------------------------------
__global__ __launch_bounds__(256)
void flash_attn(const ushort_t* __restrict__ qkv, const ushort_t* __restrict__ vtg,
                ushort_t* __restrict__ ao)
{
  __shared__ ushort_t Ks[2][8 * 64 * 32];     // [buf][kc*64+row][32]
  __shared__ ushort_t Vs[2][2 * 256 * 32];    // [buf][c*256+d][32]
  __shared__ ushort_t Ph[4][16][80];          // wave-private P hi
  __shared__ ushort_t Pl[4][16][80];          // wave-private P lo
  const int qt = (int)gridDim.x - 1 - blockIdx.x;   // heavy-first
  const int t0 = qt << 6;
  const int bh = blockIdx.y;
  const int b = bh >> 2, h = bh & 3;
  const int nIter = qt + 1;
  const int tid = threadIdx.x;
  const int wv = tid >> 6, ln = tid & 63;
  const int lrow = ln & 15, quad = ln >> 4;

  s16x8 qf[8];
  {
    const ushort_t* qrow = qkv + (size_t)(b * T_ + t0 + wv * 16 + lrow) * 3072
                           + h * 256 + quad * 8;
#pragma unroll
    for (int kc = 0; kc < 8; ++kc)
      qf[kc] = *(const s16x8*)(qrow + kc * 32);
  }

  const ushort_t* kg = qkv + (size_t)(b * T_) * 3072 + 1024 + h * 256;
  const ushort_t* vg = vtg + (size_t)bh * 131072;

  auto issue_k = [&](int i, int buf) {
#pragma unroll
    for (int iss = 0; iss < 8; ++iss) {
      const int R = 128 * wv + 16 * iss + (ln >> 2);
      const ushort_t* g = kg + (size_t)(64 * i + (R & 63)) * 3072
                          + (R >> 6) * 32 + ((ln & 3) << 3);
      ushort_t* l = &Ks[buf][(128 * wv + 16 * iss) * 32];
      __builtin_amdgcn_global_load_lds((gas_ptr)(const void*)g,
                                       (lds_ptr)(void*)l, 16, 0, 0);
    }
  };
  auto issue_v = [&](int i, int buf) {
#pragma unroll
    for (int iss = 0; iss < 8; ++iss) {   // 8 x 512 = full 4096/wave
      const ushort_t* g = vg + (size_t)i * 16384 + wv * 4096 + iss * 512 + ln * 8;
      ushort_t* l = &Vs[buf][wv * 4096 + iss * 512];
      __builtin_amdgcn_global_load_lds((gas_ptr)(const void*)g,
                                       (lds_ptr)(void*)l, 16, 0, 0);
    }
  };

  issue_k(0, 0);
  issue_v(0, 0);

  f32x4 o[16] = {};
  float Mx[4], L[4];
#pragma unroll
  for (int r = 0; r < 4; ++r) { Mx[r] = -3.0e38f; L[r] = 0.f; }

  for (int it = 0; it < nIter; ++it) {
    const int buf = it & 1;
    __syncthreads();   // vmcnt(0)+barrier: tile `it` fully resident
    if (it + 1 < nIter) { issue_k(it + 1, buf ^ 1); issue_v(it + 1, buf ^ 1); }

    // S = Q.K^T
    f32x4 s[4] = {};
#pragma unroll
    for (int kc = 0; kc < 8; ++kc)
#pragma unroll
      for (int j = 0; j < 4; ++j) {
        const s16x8 bfv = *(const s16x8*)(&Ks[buf][(kc * 64 + 16 * j + lrow) * 32
                                                   + quad * 8]);
        s[j] = __builtin_amdgcn_mfma_f32_16x16x32_bf16(qf[kc], bfv, s[j], 0, 0, 0);
      }

    const bool diag = (it == qt);
#pragma unroll
    for (int j = 0; j < 4; ++j)
#pragma unroll
      for (int r = 0; r < 4; ++r) {
        float v = s[j][r] * 0.0625f;
        if (diag && (16 * j + lrow > 16 * wv + quad * 4 + r)) v = -INFINITY;
        s[j][r] = v;
      }

    // online softmax (row = quad*4+r, spread over the quad's 16 lanes)
    float alpha[4];
#pragma unroll
    for (int r = 0; r < 4; ++r) {
      float m = fmaxf(fmaxf(s[0][r], s[1][r]), fmaxf(s[2][r], s[3][r]));
      m = fmaxf(m, __shfl_xor(m, 1));
      m = fmaxf(m, __shfl_xor(m, 2));
      m = fmaxf(m, __shfl_xor(m, 4));
      m = fmaxf(m, __shfl_xor(m, 8));
      const float mn = fmaxf(Mx[r], m);
      alpha[r] = __expf(Mx[r] - mn);
      Mx[r] = mn;
      float l = 0.f;
#pragma unroll
      for (int j = 0; j < 4; ++j) {
        const float p = __expf(s[j][r] - mn);
        s[j][r] = p;
        l += p;
      }
      l += __shfl_xor(l, 1);
      l += __shfl_xor(l, 2);
      l += __shfl_xor(l, 4);
      l += __shfl_xor(l, 8);
      L[r] = L[r] * alpha[r] + l;
    }

    // P -> LDS as hi+lo bf16 pair (C-layout -> A-layout); rescale O
#pragma unroll
    for (int j = 0; j < 4; ++j)
#pragma unroll
      for (int r = 0; r < 4; ++r) {
        const float p = s[j][r];
        const ushort_t hi = f2bf(p);
        Ph[wv][quad * 4 + r][16 * j + lrow] = hi;
        Pl[wv][quad * 4 + r][16 * j + lrow] = f2bf(p - bf2f(hi));
      }
#pragma unroll
    for (int jd = 0; jd < 16; ++jd)
#pragma unroll
      for (int r = 0; r < 4; ++r)
        o[jd][r] *= alpha[r];

    // O += (P_hi + P_lo).V
#pragma unroll
    for (int c = 0; c < 2; ++c) {
      const s16x8 ph = *(const s16x8*)(&Ph[wv][lrow][32 * c + quad * 8]);
      const s16x8 pl = *(const s16x8*)(&Pl[wv][lrow][32 * c + quad * 8]);
#pragma unroll
      for (int jd = 0; jd < 16; ++jd) {
        const s16x8 vb = *(const s16x8*)(&Vs[buf][(c * 256 + 16 * jd + lrow) * 32
                                                  + quad * 8]);
        o[jd] = __builtin_amdgcn_mfma_f32_16x16x32_bf16(ph, vb, o[jd], 0, 0, 0);
        o[jd] = __builtin_amdgcn_mfma_f32_16x16x32_bf16(pl, vb, o[jd], 0, 0, 0);
      }
    }
  }

  float inv[4];
#pragma unroll
  for (int r = 0; r < 4; ++r) inv[r] = 1.f / L[r];
  ushort_t* aob = ao + (size_t)(b * T_ + t0 + 16 * wv + quad * 4) * 1024 + h * 256;
#pragma unroll
  for (int jd = 0; jd < 16; ++jd)
#pragma unroll
    for (int r = 0; r < 4; ++r)
      aob[(size_t)r * 1024 + 16 * jd + lrow] = f2bf(o[jd][r] * inv[r]);
}

// ---------------------------------------------------------------------------
// fp32 tiled GEMM (tiny correction MLP only, M=16).
// ---------------------------------------------------------------------------
__global__ __launch_bounds__(256)
void gemm_bt(const float* __restrict__ A, const float* __restrict__ Bt,
             const float* __restrict__ bias, float* __restrict__ out,
             int M, int N, int K, int flags)
{
  __shared__ float As[16][68];
  __shared__ float Bs[16][68];
  const int n0 = blockIdx.x << 6;
  const int m0 = blockIdx.y << 6;
  const int tx = threadIdx.x, ty = threadIdx.y;
  const int tid = (ty << 4) + tx;
  const int lr = tid >> 2;
  const int lc = (tid & 3) << 2;
  float c[4][4] = {};
  for (int k0 = 0; k0 < K; k0 += 16) {
    float4 av = make_float4(0.f, 0.f, 0.f, 0.f);
    if (m0 + lr < M)
      av = *(const float4*)(A + (size_t)(m0 + lr) * K + k0 + lc);
    const float4 bv = *(const float4*)(Bt + (size_t)(n0 + lr) * K + k0 + lc);
    As[lc + 0][lr] = av.x; As[lc + 1][lr] = av.y;
    As[lc + 2][lr] = av.z; As[lc + 3][lr] = av.w;
    Bs[lc + 0][lr] = bv.x; Bs[lc + 1][lr] = bv.y;
    Bs[lc + 2][lr] = bv.z; Bs[lc + 3][lr] = bv.w;
    __syncthreads();
#pragma unroll
    for (int k = 0; k < 16; ++k) {
      const float4 a = *(const float4*)(&As[k][ty << 2]);
      const float4 b = *(const float4*)(&Bs[k][tx << 2]);
      c[0][0] += a.x*b.x; c[0][1] += a.x*b.y; c[0][2] += a.x*b.z; c[0][3] += a.x*b.w;
      c[1][0] += a.y*b.x; c[1][1] += a.y*b.y; c[1][2] += a.y*b.z; c[1][3] += a.y*b.w;
      c[2][0] += a.z*b.x; c[2][1] += a.z*b.y; c[2][2] += a.z*b.z; c[2][3] += a.z*b.w;
      c[3][0] += a.w*b.x; c[3][1] += a.w*b.y; c[3][2] += a.w*b.z; c[3][3] += a.w*b.w;
    }
    __syncthreads();
  }
  const int n = n0 + (tx << 2);
  const float4 bb = *(const float4*)(bias + n);
#pragma unroll
  for (int i = 0; i < 4; ++i) {
    const int m = m0 + (ty << 2) + i;
    if (m >= M) break;
    float4 v = make_float4(c[i][0] + bb.x, c[i][1] + bb.y,
                           c[i][2] + bb.z, c[i][3] + bb.w);
    if (flags & GF_RELU) {
      v.x = fmaxf(v.x, 0.f); v.y = fmaxf(v.y, 0.f);
      v.z = fmaxf(v.z, 0.f); v.w = fmaxf(v.w, 0.f);
    }
    *(float4*)(out + (size_t)m * N + n) = v;
  }
}

// ---------------------------------------------------------------------------
__global__ __launch_bounds__(256)
void layernorm_k(const float* __restrict__ in, const float* __restrict__ g,
                 const float* __restrict__ bta, ushort_t* __restrict__ outb)
{
  const int row = blockIdx.x;
  const int tid = threadIdx.x;
  const int wave = tid >> 6, lane = tid & 63;
  const float4 v = *(const float4*)(in + (size_t)row * D_ + (tid << 2));
  float s = v.x + v.y + v.z + v.w;
  float ss = v.x*v.x + v.y*v.y + v.z*v.z + v.w*v.w;
  for (int off = 32; off; off >>= 1) {
    s  += __shfl_down(s, off, 64);
    ss += __shfl_down(ss, off, 64);
  }
  __shared__ float ra[4], rb[4];
  if (!lane) { ra[wave] = s; rb[wave] = ss; }
  __syncthreads();
  s  = ra[0] + ra[1] + ra[2] + ra[3];
  ss = rb[0] + rb[1] + rb[2] + rb[3];
  const float mu = s * (1.f / (float)D_);
  const float var = ss * (1.f / (float)D_) - mu * mu;
  const float rstd = rsqrtf(var + EPS_);
  const float4 gv = *(const float4*)(g + (tid << 2));
  const float4 bv = *(const float4*)(bta + (tid << 2));
  ushort4 o;
  o.x = f2bf((v.x - mu) * rstd * gv.x + bv.x);
  o.y = f2bf((v.y - mu) * rstd * gv.y + bv.y);
  o.z = f2bf((v.z - mu) * rstd * gv.z + bv.z);
  o.w = f2bf((v.w - mu) * rstd * gv.w + bv.w);
  *(ushort4*)(outb + (size_t)row * D_ + (tid << 2)) = o;
}

__global__ __launch_bounds__(256)
void head2_sigmoid(const float* __restrict__ h1, const float* __restrict__ w2,
                   const float* __restrict__ b2, float* __restrict__ sout)
{
  const int tid = threadIdx.x;
  const int wave = tid >> 6, lane = tid & 63;
  const int m = (blockIdx.x << 2) + wave;
  const float* hr = h1 + (size_t)m * 512;
  float s = 0.f;
#pragma unroll
  for (int i = 0; i < 8; ++i) s += hr[i * 64 + lane] * w2[i * 64 + lane];
  for (int off = 32; off; off >>= 1) s += __shfl_down(s, off, 64);
  if (!lane) sout[m] = 1.f / (1.f + expf(-(s + b2[0])));
}

__global__ __launch_bounds__(256)
void select_worst(const float* __restrict__ s, int* __restrict__ w,
                  int* __restrict__ hasbad, int* __restrict__ counts)
{
  const int b = blockIdx.x, tid = threadIdx.x;
  const float* sr = s + b * T_;
  float bv = INFINITY; int bi = 0;
  for (int i = tid; i < T_; i += 256) {
    const float v = sr[i];
    const float cand = (v < THRESH_) ? v : INFINITY;
    if (cand < bv || (cand == bv && i < bi)) { bv = cand; bi = i; }
  }
  __shared__ float rv[256];
  __shared__ int ri[256];
  rv[tid] = bv; ri[tid] = bi;
  __syncthreads();
  for (int str = 128; str; str >>= 1) {
    if (tid < str) {
      const float v2 = rv[tid + str]; const int i2 = ri[tid + str];
      if (v2 < rv[tid] || (v2 == rv[tid] && i2 < ri[tid])) { rv[tid] = v2; ri[tid] = i2; }
    }
    __syncthreads();
  }
  if (!tid) {
    const int bad = (rv[0] < INFINITY) ? 1 : 0;
    w[b] = ri[0];
    hasbad[b] = bad;
    counts[b] += bad;
  }
}

__global__ __launch_bounds__(256)
void gather_cinp(const float* __restrict__ corr, const int* __restrict__ w,
                 float* __restrict__ cinp)
{
  const int b = blockIdx.x, tid = threadIdx.x;
  const int wi = w[b];
  const float* base = corr + (size_t)b * T_ * D_;
  const int nv = 3 - (wi == 0 ? 1 : 0) - (wi == T_ - 1 ? 1 : 0);
  const float inv = 1.f / (float)nv;
  const int d = tid << 2;
  const float4 cur = *(const float4*)(base + (size_t)wi * D_ + d);
  float4 acc = cur;
  if (wi > 0) {
    const float4 p = *(const float4*)(base + (size_t)(wi - 1) * D_ + d);
    acc.x += p.x; acc.y += p.y; acc.z += p.z; acc.w += p.w;
  }
  if (wi < T_ - 1) {
    const float4 p = *(const float4*)(base + (size_t)(wi + 1) * D_ + d);
    acc.x += p.x; acc.y += p.y; acc.z += p.z; acc.w += p.w;
  }
  acc.x *= inv; acc.y *= inv; acc.z *= inv; acc.w *= inv;
  *(float4*)(cinp + (size_t)b * (2 * D_) + d) = cur;
  *(float4*)(cinp + (size_t)b * (2 * D_) + D_ + d) = acc;
}

__global__ __launch_bounds__(256)
void apply_corr(float* __restrict__ corr, const int* __restrict__ w,
                const int* __restrict__ hasbad, const float* __restrict__ ns)
{
  const int b = blockIdx.x;
  if (!hasbad[b]) return;
  const int wi = w[b], tid = threadIdx.x;
  *(float4*)(corr + (size_t)(b * T_ + wi) * D_ + (tid << 2)) =
      *(const float4*)(ns + (size_t)b * D_ + (tid << 2));
}

__global__ __launch_bounds__(256)
void init_copy(const float* __restrict__ chain, float* __restrict__ corr,
               int* __restrict__ counts)
{
  const size_t i = ((size_t)blockIdx.x * 256 + threadIdx.x) << 2;
  *(float4*)(corr + i) = *(const float4*)(chain + i);
  if (blockIdx.x == 0 && threadIdx.x < B_) counts[threadIdx.x] = 0;
}

__global__ __launch_bounds__(256)
void finalize_k(const float* __restrict__ s0, const float* __restrict__ fs,
                const int* __restrict__ cnt, float* __restrict__ oc,
                float* __restrict__ oi)
{
  const int b = blockIdx.x, tid = threadIdx.x;
  const int wave = tid >> 6, lane = tid & 63;
  float a = s0[b * T_ + tid] + s0[b * T_ + tid + 256];
  float c = fs[b * T_ + tid] + fs[b * T_ + tid + 256];
  for (int off = 32; off; off >>= 1) {
    a += __shfl_down(a, off, 64);
    c += __shfl_down(c, off, 64);
  }
  __shared__ float ra[4], rc[4];
  if (!lane) { ra[wave] = a; rc[wave] = c; }
  __syncthreads();
  if (!tid) {
    const float as = ra[0] + ra[1] + ra[2] + ra[3];
    const float cs = rc[0] + rc[1] + rc[2] + rc[3];
    oc[b] = (float)cnt[b];
    oi[b] = (cs > as) ? 1.f : 0.f;
  }
}

// ---------------------------------------------------------------------------
extern "C" void kernel_launch(void* const* d_in, const int* in_sizes, int n_in,
                              void* d_out, int out_size, void* d_ws, size_t ws_size,
                              hipStream_t stream)
{
  const float* chain  = (const float*)d_in[0];
  const float* Wqkv   = (const float*)d_in[1];
  const float* bqkv   = (const float*)d_in[2];
  const float* Wo     = (const float*)d_in[3];
  const float* bo     = (const float*)d_in[4];
  const float* ln1g   = (const float*)d_in[5];
  const float* ln1b   = (const float*)d_in[6];
  const float* W1     = (const float*)d_in[7];
  const float* b1     = (const float*)d_in[8];
  const float* W2     = (const float*)d_in[9];
  const float* b2     = (const float*)d_in[10];
  const float* ln2g   = (const float*)d_in[11];
  const float* ln2b   = (const float*)d_in[12];
  const float* rhW1   = (const float*)d_in[13];
  const float* rhb1   = (const float*)d_in[14];
  const float* rhW2   = (const float*)d_in[15];
  const float* rhb2   = (const float*)d_in[16];
  const float* corW1  = (const float*)d_in[17];
  const float* corb1  = (const float*)d_in[18];
  const float* corW2  = (const float*)d_in[19];
  const float* corb2  = (const float*)d_in[20];

  float* ws = (float*)d_ws;
  // RegionB [0 .. 12,582,912): QKV16 bf16 (Q,K) / PRE f32 / E f32
  ushort_t* QKV16 = (ushort_t*)ws;
  float*    PRE   = ws;
  float*    E     = ws;
  // RegionH [12,582,912 .. 29,360,128): Hb bf16 FF hidden (FF1->FF2)
  //   ALIASED with Vtg bf16 (QKV-gemm -> flash) — live ranges disjoint.
  ushort_t* Hb    = (ushort_t*)(ws + 12582912);
  ushort_t* Vtg   = (ushort_t*)(ws + 12582912);   // 8,388,608 ushorts
  // Xb bf16 activations [29,360,128 .. 33,554,432)
  ushort_t* Xb    = (ushort_t*)(ws + 29360128);
  // AOb bf16 / HH f32 / run_iter scratch [33,554,432 .. 37,748,736)
  ushort_t* AOb   = (ushort_t*)(ws + 33554432);
  float*    HH    = ws + 33554432;
  float*    cinp  = ws + 33554432;
  float*    corrH = cinp + 32768;
  float*    nstep = corrH + 32768;
  // bf16 weights blob [37,748,736 .. 50,593,792)
  ushort_t* W16     = (ushort_t*)(ws + 37748736);
  ushort_t* Wqkv16  = W16;
  ushort_t* Wo16    = W16 + 6291456;
  ushort_t* W116    = W16 + 8388608;
  ushort_t* W216    = W16 + 16777216;
  ushort_t* rhW116  = W16 + 25165824;
  // small persistent buffers
  float* s0buf = ws + 50593792;
  float* sbuf  = s0buf + 8192;
  int* wbuf   = (int*)(sbuf + 8192);
  int* badbuf = wbuf + 16;
  int* cntbuf = badbuf + 16;

  float* outCorr   = (float*)d_out;
  float* outCounts = outCorr + 8388608;
  float* outFS     = outCounts + 16;
  float* outImpr   = outFS + 8192;

  const dim3 blk2(16, 16);
  const dim3 blk1(256);

  cvt_f32_bf16<<<dim3(6144), blk1, 0, stream>>>(Wqkv, Wqkv16, 6291456);
  cvt_f32_bf16<<<dim3(2048), blk1, 0, stream>>>(Wo,   Wo16,   2097152);
  cvt_f32_bf16<<<dim3(8192), blk1, 0, stream>>>(W1,   W116,   8388608);
  cvt_f32_bf16<<<dim3(8192), blk1, 0, stream>>>(W2,   W216,   8388608);
  cvt_f32_bf16<<<dim3(512),  blk1, 0, stream>>>(rhW1, rhW116, 524288);

  auto run_prm = [&](const float* xin, float* scoresOut) {
    cvt_f32_bf16<<<dim3(8192), blk1, 0, stream>>>(xin, Xb, 8388608);
    for (int l = 0; l < 2; ++l) {
      gemm_bf16<<<dim3(24, 64), blk1, 0, stream>>>(
          Xb, Wqkv16 + (size_t)l * 3 * D_ * D_, bqkv + (size_t)l * 3 * D_,
          nullptr, nullptr, QKV16, Vtg, M_, 3 * D_, D_,
          GF_OUTBF16 | GF_SPLITV);
      flash_attn<<<dim3(8, 64), blk1, 0, stream>>>(QKV16, Vtg, AOb);
      gemm_bf16<<<dim3(8, 64), blk1, 0, stream>>>(
          AOb, Wo16 + (size_t)l * D_ * D_, bo + (size_t)l * D_,
          Xb, PRE, nullptr, nullptr, M_, D_, D_, GF_RES);
      layernorm_k<<<dim3(M_), blk1, 0, stream>>>(PRE, ln1g + l * D_,
                                                 ln1b + l * D_, Xb);
      gemm_bf16<<<dim3(32, 64), blk1, 0, stream>>>(
          Xb, W116 + (size_t)l * FF_ * D_, b1 + (size_t)l * FF_,
          nullptr, nullptr, Hb, nullptr, M_, FF_, D_, GF_RELU | GF_OUTBF16);
      gemm_bf16<<<dim3(8, 64), blk1, 0, stream>>>(
          Hb, W216 + (size_t)l * D_ * FF_, b2 + (size_t)l * D_,
          Xb, E, nullptr, nullptr, M_, D_, FF_, GF_RES);
      layernorm_k<<<dim3(M_), blk1, 0, stream>>>(E, ln2g + l * D_,
                                                 ln2b + l * D_, Xb);
    }
    gemm_bf16<<<dim3(4, 64), blk1, 0, stream>>>(
        Xb, rhW116, rhb1, nullptr, HH, nullptr, nullptr, M_, 512, D_, GF_RELU);
    head2_sigmoid<<<dim3(M_ / 4), blk1, 0, stream>>>(HH, rhW2, rhb2, scoresOut);
  };

  auto run_iter = [&](const float* sPtr) {
    select_worst<<<dim3(B_), blk1, 0, stream>>>(sPtr, wbuf, badbuf, cntbuf);
    gather_cinp<<<dim3(B_), blk1, 0, stream>>>(outCorr, wbuf, cinp);
    gemm_bt<<<dim3(32, 1), blk2, 0, stream>>>(cinp, corW1, corb1, corrH,
                                              B_, 2 * D_, 2 * D_, GF_RELU);
    gemm_bt<<<dim3(16, 1), blk2, 0, stream>>>(corrH, corW2, corb2, nstep,
                                              B_, D_, 2 * D_, 0);
    apply_corr<<<dim3(B_), blk1, 0, stream>>>(outCorr, wbuf, badbuf, nstep);
  };

  init_copy<<<dim3(8192), blk1, 0, stream>>>(chain, outCorr, cntbuf);

  run_prm(chain, s0buf);
  run_iter(s0buf);
  run_prm(outCorr, sbuf);
  run_iter(sbuf);
  run_prm(outCorr, sbuf);
  run_iter(sbuf);
  run_prm(outCorr, outFS);
  finalize_k<<<dim3(B_), blk1, 0, stream>>>(s0buf, outFS, cntbuf,
                                            outCounts, outImpr);
  (void)in_sizes; (void)n_in; (void)out_size; (void)ws_size;
}